// Round 10
// baseline (5135.500 us; speedup 1.0000x reference)
//
#include <hip/hip_runtime.h>
#include <hip/hip_cooperative_groups.h>
#include <math.h>

// ---------------------------------------------------------------------------
// DiscriminatorLSTM: B=128, T=64, FEAT=4096, FUSION=1024, H=1024, C=2
//
// Split-bf16 (hi/lo) MFMA: v = hi + lo, A*B ~= ah*bh + al*bh + ah*bl
//
// prep:    split_pair: W_feat (1024x4096 = 1,048,576 float4) -> Wfh/Wfl
// Phase A: Fh/Fl = split(relu(X @ W_feat^T + b_feat))
// Phase B: Gx(f32) = F @ W_ih^T + b_ih
// pack_whh2 (AFTER B, aliases Fh region): W_hh -> 16-col B-fragment pack
// Phase C: ONE persistent cooperative kernel (grid 256 = 1 WG/CU, 512 thr):
//          W_hh slice held in VGPRs (128/lane) across all 64 steps,
//          c held in VGPRs (1/thread), one grid.sync() per step.
//
// ws layout (sizes verified):
//   [0,16M)    Fh (8192x1024 u16) | after B: Wf2 hi [0,8M) lo [8,16M)
//   [16,32M)   Fl                 | after B: hfrag @16M (1MB dbuf)
//   [32,160M)  Gx f32 (128 MB)    | BEFORE B: Wfh @32M (8MB), Wfl @40M (8MB)
// ---------------------------------------------------------------------------

namespace cg = cooperative_groups;

typedef __attribute__((ext_vector_type(8))) short short8v;   // 8 bf16
typedef __attribute__((ext_vector_type(4))) float f32x4;
typedef unsigned short u16;

#define WF_LO_OFF 8388608u
#define HF_BUF    524288
#define HF_HL     262144
#define HF_MT     32768

__device__ __forceinline__ u16 f2bf(float f) {   // RNE f32->bf16
    unsigned u = __builtin_bit_cast(unsigned, f);
    u = (u + 0x7fffu + ((u >> 16) & 1u)) >> 16;
    return (u16)u;
}
__device__ __forceinline__ float bf2f(u16 b) {
    unsigned u = ((unsigned)b) << 16;
    return __builtin_bit_cast(float, u);
}
__device__ __forceinline__ void split8(const float* f, short8v& hi, short8v& lo) {
#pragma unroll
    for (int e = 0; e < 8; ++e) {
        u16 h = f2bf(f[e]);
        hi[e] = (short)h;
        lo[e] = (short)f2bf(f[e] - bf2f(h));
    }
}

// ---------------- elementwise f32 -> (hi,lo) bf16 split --------------------
__global__ void split_pair(const float* __restrict__ src,
                           u16* __restrict__ dh, u16* __restrict__ dl, int n4) {
    int i = blockIdx.x * blockDim.x + threadIdx.x;
    if (i >= n4) return;
    float4 v = ((const float4*)src)[i];
    float f[4] = {v.x, v.y, v.z, v.w};
    u16 h[4], lo[4];
#pragma unroll
    for (int e = 0; e < 4; ++e) {
        h[e]  = f2bf(f[e]);
        lo[e] = f2bf(f[e] - bf2f(h[e]));
    }
    ((ushort4*)dh)[i] = make_ushort4(h[0], h[1], h[2], h[3]);
    ((ushort4*)dl)[i] = make_ushort4(lo[0], lo[1], lo[2], lo[3]);
}

// ------------------- split-bf16 MFMA GEMM  (C = A @ B^T) -------------------
// Fragment LDS position swizzle: p = (row ^ (koct<<1)) | (koct<<4).
template<bool A_PRESPLIT, bool B_PRESPLIT, bool RELU, bool OUT_SPLIT>
__global__ __launch_bounds__(256)
void gemm_mfma(const float* __restrict__ Af,
               const u16* __restrict__ Ah, const u16* __restrict__ Al, int lda,
               const float* __restrict__ Bf,
               const u16* __restrict__ Bh, const u16* __restrict__ Bl, int ldb,
               const float* __restrict__ bias,
               float* __restrict__ C, u16* __restrict__ Ch, u16* __restrict__ Cl,
               int ldc, int K)
{
    __shared__ short8v AsH[8][64];
    __shared__ short8v AsL[8][64];
    __shared__ short8v BsH[8][64];
    __shared__ short8v BsL[8][64];

    const int tid = threadIdx.x;
    const int l   = tid & 63;
    const int w   = tid >> 6;
    const int wm  = w & 1, wn = w >> 1;
    const int bm  = blockIdx.x * 128, bn = blockIdx.y * 128;

    const int sm    = tid >> 2;
    const int sk8   = (tid & 3) * 8;
    const int koct_s = sk8 >> 3;
    const int slane = ((sm & 15) ^ (koct_s << 1)) | (koct_s << 4);  // swizzled
    const int smf   = sm >> 4;
    const int lsw   = ((l & 15) ^ ((l >> 4) << 1)) | (l & 48);      // read side

    f32x4 acc[4][4];
#pragma unroll
    for (int i = 0; i < 4; ++i)
#pragma unroll
        for (int j = 0; j < 4; ++j)
#pragma unroll
            for (int r = 0; r < 4; ++r) acc[i][j][r] = 0.f;

    for (int k0 = 0; k0 < K; k0 += 32) {
        if constexpr (A_PRESPLIT) {
            const size_t o0 = (size_t)(bm + sm) * lda + k0 + sk8;
            const size_t o1 = (size_t)(bm + sm + 64) * lda + k0 + sk8;
            AsH[smf][slane]     = *(const short8v*)(Ah + o0);
            AsL[smf][slane]     = *(const short8v*)(Al + o0);
            AsH[smf + 4][slane] = *(const short8v*)(Ah + o1);
            AsL[smf + 4][slane] = *(const short8v*)(Al + o1);
        } else {
            float fa[8], fb[8];
            const float* p0 = Af + (size_t)(bm + sm) * lda + k0 + sk8;
            const float* p1 = Af + (size_t)(bm + sm + 64) * lda + k0 + sk8;
            *(float4*)(fa)     = *(const float4*)(p0);
            *(float4*)(fa + 4) = *(const float4*)(p0 + 4);
            *(float4*)(fb)     = *(const float4*)(p1);
            *(float4*)(fb + 4) = *(const float4*)(p1 + 4);
            short8v hi, lo;
            split8(fa, hi, lo);
            AsH[smf][slane] = hi; AsL[smf][slane] = lo;
            split8(fb, hi, lo);
            AsH[smf + 4][slane] = hi; AsL[smf + 4][slane] = lo;
        }
        if constexpr (B_PRESPLIT) {
            const size_t o0 = (size_t)(bn + sm) * ldb + k0 + sk8;
            const size_t o1 = (size_t)(bn + sm + 64) * ldb + k0 + sk8;
            BsH[smf][slane]     = *(const short8v*)(Bh + o0);
            BsL[smf][slane]     = *(const short8v*)(Bl + o0);
            BsH[smf + 4][slane] = *(const short8v*)(Bh + o1);
            BsL[smf + 4][slane] = *(const short8v*)(Bl + o1);
        } else {
            float fa[8], fb[8];
            const float* p0 = Bf + (size_t)(bn + sm) * ldb + k0 + sk8;
            const float* p1 = Bf + (size_t)(bn + sm + 64) * ldb + k0 + sk8;
            *(float4*)(fa)     = *(const float4*)(p0);
            *(float4*)(fa + 4) = *(const float4*)(p0 + 4);
            *(float4*)(fb)     = *(const float4*)(p1);
            *(float4*)(fb + 4) = *(const float4*)(p1 + 4);
            short8v hi, lo;
            split8(fa, hi, lo);
            BsH[smf][slane] = hi; BsL[smf][slane] = lo;
            split8(fb, hi, lo);
            BsH[smf + 4][slane] = hi; BsL[smf + 4][slane] = lo;
        }
        __syncthreads();

        short8v a_h[4], a_l[4];
#pragma unroll
        for (int i = 0; i < 4; ++i) {
            a_h[i] = AsH[wm * 4 + i][lsw];
            a_l[i] = AsL[wm * 4 + i][lsw];
        }
#pragma unroll
        for (int j = 0; j < 4; ++j) {
            const short8v b_h = BsH[wn * 4 + j][lsw];
            const short8v b_l = BsL[wn * 4 + j][lsw];
#pragma unroll
            for (int i = 0; i < 4; ++i) {
                acc[i][j] = __builtin_amdgcn_mfma_f32_16x16x32_bf16(a_h[i], b_h, acc[i][j], 0, 0, 0);
                acc[i][j] = __builtin_amdgcn_mfma_f32_16x16x32_bf16(a_l[i], b_h, acc[i][j], 0, 0, 0);
                acc[i][j] = __builtin_amdgcn_mfma_f32_16x16x32_bf16(a_h[i], b_l, acc[i][j], 0, 0, 0);
            }
        }
        __syncthreads();
    }

    const int row0 = bm + wm * 64 + (l >> 4) * 4;
    const int col0 = bn + wn * 64 + (l & 15);
#pragma unroll
    for (int i = 0; i < 4; ++i) {
#pragma unroll
        for (int j = 0; j < 4; ++j) {
            const int col = col0 + j * 16;
            const float bs = bias[col];
#pragma unroll
            for (int r = 0; r < 4; ++r) {
                const int row = row0 + i * 16 + r;
                float v = acc[i][j][r] + bs;
                if (RELU) v = fmaxf(v, 0.f);
                if (OUT_SPLIT) {
                    u16 h = f2bf(v);
                    Ch[(size_t)row * ldc + col] = h;
                    Cl[(size_t)row * ldc + col] = f2bf(v - bf2f(h));
                } else {
                    C[(size_t)row * ldc + col] = v;
                }
            }
        }
    }
}

// ----------- W_hh -> 16-col split-bf16 B-fragment pre-pack -----------------
__global__ void pack_whh2(const float* __restrict__ W, char* __restrict__ Wf) {
    int gid = blockIdx.x * blockDim.x + threadIdx.x;   // < 524288
    int l = gid & 63, fid = gid >> 6;                  // fid < 8192
    int kcl = fid & 15, kh = (fid >> 4) & 1, ngrp = (fid >> 5) & 63, g = fid >> 11;
    int n = g * 1024 + ngrp * 16 + (l & 15);
    int k = kh * 512 + kcl * 32 + (l >> 4) * 8;
    const float* src = W + (size_t)n * 1024 + k;
    short8v hi, lo;
#pragma unroll
    for (int e = 0; e < 8; ++e) {
        float v = src[e];
        u16 hb = f2bf(v);
        hi[e] = (short)hb;
        lo[e] = (short)f2bf(v - bf2f(hb));
    }
    size_t off = (size_t)fid * 1024 + (size_t)l * 16;
    *(short8v*)(Wf + off) = hi;
    *(short8v*)(Wf + WF_LO_OFF + off) = lo;
}

__global__ void out_init(float* __restrict__ out, const float* __restrict__ b_cls) {
    int i = blockIdx.x * blockDim.x + threadIdx.x;
    if (i < 16384) out[i] = b_cls[i & 1];
}

// ------------------ persistent cooperative LSTM (phase C) ------------------
// Grid 256 (1 WG/CU, LDS-forced), 512 thr. WG (mh=bid>>6, ngrp=bid&63):
// rows mh*32..+32, per-gate cols ngrp*16..+16. Wave w: gate g=w&3, kh=w>>2.
// W_hh slice in VGPRs (32 short8v/lane), c in VGPR (1/thread), 64-step loop
// with one grid.sync() per step.
__global__ __launch_bounds__(512)
void lstm_persistent(const float* __restrict__ Gx,
                     const float* __restrict__ b_hh,
                     const char*  __restrict__ Wf,
                     char*        __restrict__ hfrag,
                     const float* __restrict__ Wc,
                     float*       __restrict__ out)
{
    __shared__ short8v Hs[128][64];          // 128 KB: s = (hl*2+mf)*32 + kc
    __shared__ float gates_s[2][4][32][16];  // 16 KB
    __shared__ float h_s[32][16];            // 2 KB

    cg::grid_group grid = cg::this_grid();

    const int tid = threadIdx.x, bid = blockIdx.x;
    const int w = tid >> 6, l = tid & 63;
    const int g = w & 3, kh = w >> 2;
    const int ngrp = bid & 63, mh = bid >> 6;
    const int lhi = l >> 4;
    const int llo = l & 15;

    // cell-ownership: thread -> (row, col), constant across steps
    const int r_c  = tid >> 4;
    const int cw_c = tid & 15;
    const int row_c = mh * 32 + r_c;
    const int col_c = ngrp * 16 + cw_c;

    // ---- hoist invariants into registers ----
    // W_hh slice for this wave: 16 kcl x (hi,lo)
    short8v Wr[32];
    {
        const char* wb = Wf + (size_t)((g * 64 + ngrp) * 2 + kh) * 16384 + (size_t)l * 16;
#pragma unroll
        for (int kcl = 0; kcl < 16; ++kcl) {
            Wr[kcl * 2]     = *(const short8v*)(wb + kcl * 1024);
            Wr[kcl * 2 + 1] = *(const short8v*)(wb + kcl * 1024 + WF_LO_OFF);
        }
    }
    float bh_reg[4];
#pragma unroll
    for (int gg = 0; gg < 4; ++gg) bh_reg[gg] = b_hh[gg * 1024 + col_c];
    const float wc0 = Wc[col_c];
    const float wc1 = Wc[1024 + col_c];
    float c_reg = 0.f;

    for (int t = 0; t < 64; ++t) {
        f32x4 aA0, aB0, aA1, aB1;
#pragma unroll
        for (int r = 0; r < 4; ++r) { aA0[r] = 0.f; aB0[r] = 0.f; aA1[r] = 0.f; aB1[r] = 0.f; }

        if (t > 0) {
            // stage h hi/lo fragments for m_tiles {2mh, 2mh+1}
            const char* hbase = hfrag + ((t - 1) & 1) * HF_BUF;
#pragma unroll
            for (int it = 0; it < 16; ++it) {
                const int u  = tid + it * 512;      // 0..8191
                const int s  = u >> 6;              // hl = s>>6, mf = (s>>5)&1, kc = s&31
                const int ln = u & 63;
                Hs[s][ln] = *(const short8v*)(hbase
                            + (size_t)(s >> 6) * HF_HL
                            + (size_t)(2 * mh + ((s >> 5) & 1)) * HF_MT
                            + (size_t)(s & 31) * 1024 + (size_t)ln * 16);
            }
            __syncthreads();

#pragma unroll
            for (int kcl = 0; kcl < 16; ++kcl) {
                const short8v bh = Wr[kcl * 2];
                const short8v bl = Wr[kcl * 2 + 1];
                const int kc = kh * 16 + kcl;
                const short8v ah0 = Hs[kc][l];
                const short8v ah1 = Hs[32 + kc][l];
                const short8v al0 = Hs[64 + kc][l];
                const short8v al1 = Hs[96 + kc][l];
                aA0 = __builtin_amdgcn_mfma_f32_16x16x32_bf16(ah0, bh, aA0, 0, 0, 0);
                aB0 = __builtin_amdgcn_mfma_f32_16x16x32_bf16(al0, bh, aB0, 0, 0, 0);
                aB0 = __builtin_amdgcn_mfma_f32_16x16x32_bf16(ah0, bl, aB0, 0, 0, 0);
                aA1 = __builtin_amdgcn_mfma_f32_16x16x32_bf16(ah1, bh, aA1, 0, 0, 0);
                aB1 = __builtin_amdgcn_mfma_f32_16x16x32_bf16(al1, bh, aB1, 0, 0, 0);
                aB1 = __builtin_amdgcn_mfma_f32_16x16x32_bf16(ah1, bl, aB1, 0, 0, 0);
            }
        }

        // partial gate tiles -> LDS (zeros at t==0)
#pragma unroll
        for (int r = 0; r < 4; ++r) {
            gates_s[kh][g][lhi * 4 + r][llo]      = aA0[r] + aB0[r];
            gates_s[kh][g][16 + lhi * 4 + r][llo] = aA1[r] + aB1[r];
        }
        __syncthreads();

        // LSTM cell: one element/thread, c in register
        {
            float gate[4];
#pragma unroll
            for (int gg = 0; gg < 4; ++gg) {
                const size_t gidx = ((size_t)row_c * 64 + t) * 4096
                                  + (size_t)gg * 1024 + col_c;
                gate[gg] = gates_s[0][gg][r_c][cw_c] + gates_s[1][gg][r_c][cw_c]
                         + Gx[gidx] + bh_reg[gg];
            }
            float ig = 1.f / (1.f + __expf(-gate[0]));
            float fg = 1.f / (1.f + __expf(-gate[1]));
            float gg = tanhf(gate[2]);
            float og = 1.f / (1.f + __expf(-gate[3]));
            float cn = fg * c_reg + ig * gg;
            float hn = og * tanhf(cn);
            c_reg = cn;
            h_s[r_c][cw_c] = hn;

            float s0 = hn * wc0;
            float s1 = hn * wc1;
#pragma unroll
            for (int off = 8; off > 0; off >>= 1) {
                s0 += __shfl_xor(s0, off);
                s1 += __shfl_xor(s1, off);
            }
            if (cw_c == 0) {
                float* o = out + ((size_t)row_c * 64 + t) * 2;
                atomicAdd(o,     s0);
                atomicAdd(o + 1, s1);
            }
        }
        __syncthreads();

        if (t < 63) {
            // h-fragment write (same mapping as r9)
            if (tid < 128) {
                const int idx16  = tid & 15;
                const int koct_h = (tid >> 4) & 1;
                const int mt_l   = (tid >> 5) & 1;
                const int hl     = tid >> 6;
                const int lane   = idx16 | (((ngrp & 1) * 2 + koct_h) << 4);
                short8v v;
#pragma unroll
                for (int e = 0; e < 8; ++e) {
                    float hv = h_s[mt_l * 16 + idx16][koct_h * 8 + e];
                    u16 hb_ = f2bf(hv);
                    v[e] = (short)(hl == 0 ? hb_ : f2bf(hv - bf2f(hb_)));
                }
                char* dst = hfrag + (t & 1) * HF_BUF + (size_t)hl * HF_HL
                          + (size_t)(2 * mh + mt_l) * HF_MT
                          + (size_t)(ngrp >> 1) * 1024 + (size_t)lane * 16;
                *(short8v*)dst = v;
            }
            __threadfence();   // device-scope release of h-frag writes
            grid.sync();
        }
    }
}

// ---------------------------------------------------------------------------
extern "C" void kernel_launch(void* const* d_in, const int* in_sizes, int n_in,
                              void* d_out, int out_size, void* d_ws, size_t ws_size,
                              hipStream_t stream) {
    const float* x      = (const float*)d_in[0];
    const float* W_feat = (const float*)d_in[1];
    const float* b_feat = (const float*)d_in[2];
    const float* W_ih   = (const float*)d_in[3];
    const float* b_ih   = (const float*)d_in[4];
    const float* W_hh   = (const float*)d_in[5];
    const float* b_hh   = (const float*)d_in[6];
    const float* W_cls  = (const float*)d_in[7];
    const float* b_cls  = (const float*)d_in[8];
    float* out = (float*)d_out;

    char* ws = (char*)d_ws;
    u16*  Fh  = (u16*)ws;                      // [0,16M)  8192x1024 u16
    u16*  Fl  = (u16*)(ws + 16777216);         // [16,32M)
    float* Gx = (float*)(ws + 33554432);       // [32,160M) 8192x4096 f32
    u16*  Wfh = (u16*)(ws + 33554432);         // [32,40M)  1024x4096 u16, dead at B
    u16*  Wfl = (u16*)(ws + 41943040);         // [40,48M)  dead at B
    char* Wf    = ws;                          // [0,16M)  after pack (post-B)
    char* hfrag = ws + 16777216;               // [16,17M) post-B

    // prep: W_feat = 1024x4096 = 4,194,304 floats = 1,048,576 float4 chunks
    split_pair<<<dim3(4096), dim3(256), 0, stream>>>(W_feat, Wfh, Wfl, 1048576);
    out_init<<<dim3(64), dim3(256), 0, stream>>>(out, b_cls);

    // Phase A: Fh/Fl = split(relu(X @ W_feat^T + b_feat))  M=8192 N=1024 K=4096
    gemm_mfma<false, true, true, true>
        <<<dim3(64, 8), 256, 0, stream>>>(
            x, nullptr, nullptr, 4096,
            nullptr, Wfh, Wfl, 4096, b_feat,
            nullptr, Fh, Fl, 1024, 4096);

    // Phase B: Gx = F @ W_ih^T + b_ih   M=8192 N=4096 K=1024
    gemm_mfma<true, false, false, false>
        <<<dim3(64, 32), 256, 0, stream>>>(
            nullptr, Fh, Fl, 1024,
            W_ih, nullptr, nullptr, 1024, b_ih,
            Gx, nullptr, nullptr, 4096, 1024);

    // pack W_hh fragments AFTER phase B (aliases dead Fh region)
    pack_whh2<<<dim3(2048), dim3(256), 0, stream>>>(W_hh, Wf);

    // Phase C: single persistent cooperative kernel, 64 steps internally
    {
        const float* Gx_c  = Gx;
        const float* bhh_c = b_hh;
        const char*  Wf_c  = Wf;
        char*        hf_c  = hfrag;
        const float* Wc_c  = W_cls;
        float*       out_c = out;
        void* args[] = {(void*)&Gx_c, (void*)&bhh_c, (void*)&Wf_c,
                        (void*)&hf_c, (void*)&Wc_c, (void*)&out_c};
        hipLaunchCooperativeKernel((const void*)lstm_persistent,
                                   dim3(256), dim3(512), args, 0, stream);
    }
}

// Round 11
// 1101.340 us; speedup vs baseline: 4.6630x; 4.6630x over previous
//
#include <hip/hip_runtime.h>
#include <math.h>

// ---------------------------------------------------------------------------
// DiscriminatorLSTM: B=128, T=64, FEAT=4096, FUSION=1024, H=1024, C=2
//
// Split-bf16 (hi/lo) MFMA: v = hi + lo, A*B ~= ah*bh + al*bh + ah*bl
//
// prep:    split_pair: W_feat (1024x4096 = 1,048,576 float4) -> Wfh/Wfl
// Phase A: Fh/Fl = split(relu(X @ W_feat^T + b_feat))
// Phase B: Gx(f32) = F @ W_ih^T + b_ih
// pack_whh2 (AFTER B, aliases Fh region): W_hh -> 16-col B-fragment pack
// Phase C: 64x lstm_step (round-9-proven; cooperative grid.sync variant was
//          4.6x SLOWER -- ~73 us per cross-XCD grid barrier, r10 post-mortem)
//
// NEW r11: XCD-chunked blockIdx swizzle in gemm_mfma (bijective, nwg%8==0):
//          same-N-panel blocks land on one XCD -> B-operand L2-resident.
//
// ws layout (sizes verified):
//   [0,16M)    Fh (8192x1024 u16) | after B: Wf2 hi [0,8M) lo [8,16M)
//   [16,32M)   Fl                 | after B: hfrag @16M (1MB dbuf), c @17M
//   [32,160M)  Gx f32 (128 MB)    | BEFORE B: Wfh @32M (8MB), Wfl @40M (8MB)
// ---------------------------------------------------------------------------

typedef __attribute__((ext_vector_type(8))) short short8v;   // 8 bf16
typedef __attribute__((ext_vector_type(4))) float f32x4;
typedef unsigned short u16;

#define WF_LO_OFF 8388608u
#define HF_BUF    524288
#define HF_HL     262144
#define HF_MT     32768

__device__ __forceinline__ u16 f2bf(float f) {   // RNE f32->bf16
    unsigned u = __builtin_bit_cast(unsigned, f);
    u = (u + 0x7fffu + ((u >> 16) & 1u)) >> 16;
    return (u16)u;
}
__device__ __forceinline__ float bf2f(u16 b) {
    unsigned u = ((unsigned)b) << 16;
    return __builtin_bit_cast(float, u);
}
__device__ __forceinline__ void split8(const float* f, short8v& hi, short8v& lo) {
#pragma unroll
    for (int e = 0; e < 8; ++e) {
        u16 h = f2bf(f[e]);
        hi[e] = (short)h;
        lo[e] = (short)f2bf(f[e] - bf2f(h));
    }
}

// ---------------- elementwise f32 -> (hi,lo) bf16 split --------------------
__global__ void split_pair(const float* __restrict__ src,
                           u16* __restrict__ dh, u16* __restrict__ dl, int n4) {
    int i = blockIdx.x * blockDim.x + threadIdx.x;
    if (i >= n4) return;
    float4 v = ((const float4*)src)[i];
    float f[4] = {v.x, v.y, v.z, v.w};
    u16 h[4], lo[4];
#pragma unroll
    for (int e = 0; e < 4; ++e) {
        h[e]  = f2bf(f[e]);
        lo[e] = f2bf(f[e] - bf2f(h[e]));
    }
    ((ushort4*)dh)[i] = make_ushort4(h[0], h[1], h[2], h[3]);
    ((ushort4*)dl)[i] = make_ushort4(lo[0], lo[1], lo[2], lo[3]);
}

// ------------------- split-bf16 MFMA GEMM  (C = A @ B^T) -------------------
// Fragment LDS position swizzle: p = (row ^ (koct<<1)) | (koct<<4)  [r9: kills
// the 4-way staging-write conflict, SQ_LDS_BANK_CONFLICT 5e7 -> 0].
// XCD-chunked block swizzle [r11]: newL = (L&7)*(nwg/8) + (L>>3).
template<bool A_PRESPLIT, bool B_PRESPLIT, bool RELU, bool OUT_SPLIT>
__global__ __launch_bounds__(256)
void gemm_mfma(const float* __restrict__ Af,
               const u16* __restrict__ Ah, const u16* __restrict__ Al, int lda,
               const float* __restrict__ Bf,
               const u16* __restrict__ Bh, const u16* __restrict__ Bl, int ldb,
               const float* __restrict__ bias,
               float* __restrict__ C, u16* __restrict__ Ch, u16* __restrict__ Cl,
               int ldc, int K)
{
    __shared__ short8v AsH[8][64];
    __shared__ short8v AsL[8][64];
    __shared__ short8v BsH[8][64];
    __shared__ short8v BsL[8][64];

    const int tid = threadIdx.x;
    const int l   = tid & 63;
    const int w   = tid >> 6;
    const int wm  = w & 1, wn = w >> 1;

    // XCD-chunked bijective block remap (gridDim.x == 64 in both phases)
    const int L   = blockIdx.y * gridDim.x + blockIdx.x;
    const int cpx = (gridDim.x * gridDim.y) >> 3;
    const int nL  = (L & 7) * cpx + (L >> 3);
    const int bm  = (nL & 63) * 128;
    const int bn  = (nL >> 6) * 128;

    const int sm    = tid >> 2;
    const int sk8   = (tid & 3) * 8;
    const int koct_s = sk8 >> 3;
    const int slane = ((sm & 15) ^ (koct_s << 1)) | (koct_s << 4);  // swizzled
    const int smf   = sm >> 4;
    const int lsw   = ((l & 15) ^ ((l >> 4) << 1)) | (l & 48);      // read side

    f32x4 acc[4][4];
#pragma unroll
    for (int i = 0; i < 4; ++i)
#pragma unroll
        for (int j = 0; j < 4; ++j)
#pragma unroll
            for (int r = 0; r < 4; ++r) acc[i][j][r] = 0.f;

    for (int k0 = 0; k0 < K; k0 += 32) {
        if constexpr (A_PRESPLIT) {
            const size_t o0 = (size_t)(bm + sm) * lda + k0 + sk8;
            const size_t o1 = (size_t)(bm + sm + 64) * lda + k0 + sk8;
            AsH[smf][slane]     = *(const short8v*)(Ah + o0);
            AsL[smf][slane]     = *(const short8v*)(Al + o0);
            AsH[smf + 4][slane] = *(const short8v*)(Ah + o1);
            AsL[smf + 4][slane] = *(const short8v*)(Al + o1);
        } else {
            float fa[8], fb[8];
            const float* p0 = Af + (size_t)(bm + sm) * lda + k0 + sk8;
            const float* p1 = Af + (size_t)(bm + sm + 64) * lda + k0 + sk8;
            *(float4*)(fa)     = *(const float4*)(p0);
            *(float4*)(fa + 4) = *(const float4*)(p0 + 4);
            *(float4*)(fb)     = *(const float4*)(p1);
            *(float4*)(fb + 4) = *(const float4*)(p1 + 4);
            short8v hi, lo;
            split8(fa, hi, lo);
            AsH[smf][slane] = hi; AsL[smf][slane] = lo;
            split8(fb, hi, lo);
            AsH[smf + 4][slane] = hi; AsL[smf + 4][slane] = lo;
        }
        if constexpr (B_PRESPLIT) {
            const size_t o0 = (size_t)(bn + sm) * ldb + k0 + sk8;
            const size_t o1 = (size_t)(bn + sm + 64) * ldb + k0 + sk8;
            BsH[smf][slane]     = *(const short8v*)(Bh + o0);
            BsL[smf][slane]     = *(const short8v*)(Bl + o0);
            BsH[smf + 4][slane] = *(const short8v*)(Bh + o1);
            BsL[smf + 4][slane] = *(const short8v*)(Bl + o1);
        } else {
            float fa[8], fb[8];
            const float* p0 = Bf + (size_t)(bn + sm) * ldb + k0 + sk8;
            const float* p1 = Bf + (size_t)(bn + sm + 64) * ldb + k0 + sk8;
            *(float4*)(fa)     = *(const float4*)(p0);
            *(float4*)(fa + 4) = *(const float4*)(p0 + 4);
            *(float4*)(fb)     = *(const float4*)(p1);
            *(float4*)(fb + 4) = *(const float4*)(p1 + 4);
            short8v hi, lo;
            split8(fa, hi, lo);
            BsH[smf][slane] = hi; BsL[smf][slane] = lo;
            split8(fb, hi, lo);
            BsH[smf + 4][slane] = hi; BsL[smf + 4][slane] = lo;
        }
        __syncthreads();

        short8v a_h[4], a_l[4];
#pragma unroll
        for (int i = 0; i < 4; ++i) {
            a_h[i] = AsH[wm * 4 + i][lsw];
            a_l[i] = AsL[wm * 4 + i][lsw];
        }
#pragma unroll
        for (int j = 0; j < 4; ++j) {
            const short8v b_h = BsH[wn * 4 + j][lsw];
            const short8v b_l = BsL[wn * 4 + j][lsw];
#pragma unroll
            for (int i = 0; i < 4; ++i) {
                acc[i][j] = __builtin_amdgcn_mfma_f32_16x16x32_bf16(a_h[i], b_h, acc[i][j], 0, 0, 0);
                acc[i][j] = __builtin_amdgcn_mfma_f32_16x16x32_bf16(a_l[i], b_h, acc[i][j], 0, 0, 0);
                acc[i][j] = __builtin_amdgcn_mfma_f32_16x16x32_bf16(a_h[i], b_l, acc[i][j], 0, 0, 0);
            }
        }
        __syncthreads();
    }

    const int row0 = bm + wm * 64 + (l >> 4) * 4;
    const int col0 = bn + wn * 64 + (l & 15);
#pragma unroll
    for (int i = 0; i < 4; ++i) {
#pragma unroll
        for (int j = 0; j < 4; ++j) {
            const int col = col0 + j * 16;
            const float bs = bias[col];
#pragma unroll
            for (int r = 0; r < 4; ++r) {
                const int row = row0 + i * 16 + r;
                float v = acc[i][j][r] + bs;
                if (RELU) v = fmaxf(v, 0.f);
                if (OUT_SPLIT) {
                    u16 h = f2bf(v);
                    Ch[(size_t)row * ldc + col] = h;
                    Cl[(size_t)row * ldc + col] = f2bf(v - bf2f(h));
                } else {
                    C[(size_t)row * ldc + col] = v;
                }
            }
        }
    }
}

// ----------- W_hh -> 16-col split-bf16 B-fragment pre-pack -----------------
__global__ void pack_whh2(const float* __restrict__ W, char* __restrict__ Wf) {
    int gid = blockIdx.x * blockDim.x + threadIdx.x;   // < 524288
    int l = gid & 63, fid = gid >> 6;                  // fid < 8192
    int kcl = fid & 15, kh = (fid >> 4) & 1, ngrp = (fid >> 5) & 63, g = fid >> 11;
    int n = g * 1024 + ngrp * 16 + (l & 15);
    int k = kh * 512 + kcl * 32 + (l >> 4) * 8;
    const float* src = W + (size_t)n * 1024 + k;
    short8v hi, lo;
#pragma unroll
    for (int e = 0; e < 8; ++e) {
        float v = src[e];
        u16 hb = f2bf(v);
        hi[e] = (short)hb;
        lo[e] = (short)f2bf(v - bf2f(hb));
    }
    size_t off = (size_t)fid * 1024 + (size_t)l * 16;
    *(short8v*)(Wf + off) = hi;
    *(short8v*)(Wf + WF_LO_OFF + off) = lo;
}

__global__ void out_init(float* __restrict__ out, const float* __restrict__ b_cls) {
    int i = blockIdx.x * blockDim.x + threadIdx.x;
    if (i < 16384) out[i] = b_cls[i & 1];
}

// --------------------------- fused LSTM step (r9-proven) -------------------
// 256 WGs x 512 thr. WG (mh = bid>>6, ngrp = bid&63): rows mh*32..+32,
// per-gate cols ngrp*16..+16. Wave w: gate g=w&3, K-half kh=w>>2.
__global__ __launch_bounds__(512)
void lstm_step(const float* __restrict__ Gx,
               const float* __restrict__ b_hh,
               const char*  __restrict__ Wf,
               char*        __restrict__ hfrag,
               float*       __restrict__ c,
               const float* __restrict__ Wc,
               float*       __restrict__ out,
               int t)
{
    __shared__ short8v Hs[128][64];          // 128 KB: s = (hl*2+mf)*32 + kc
    __shared__ float gates_s[2][4][32][16];  // 16 KB
    __shared__ float h_s[32][16];            // 2 KB
    __shared__ float Wc_s[2][16];

    const int tid = threadIdx.x, bid = blockIdx.x;
    const int w = tid >> 6, l = tid & 63;
    const int g = w & 3, kh = w >> 2;
    const int ngrp = bid & 63, mh = bid >> 6;

    if (tid < 32) Wc_s[tid >> 4][tid & 15] =
        Wc[(size_t)(tid >> 4) * 1024 + ngrp * 16 + (tid & 15)];

    const int lhi = l >> 4;
    const int llo = l & 15;

    f32x4 aA0, aB0, aA1, aB1;
#pragma unroll
    for (int r = 0; r < 4; ++r) { aA0[r] = 0.f; aB0[r] = 0.f; aA1[r] = 0.f; aB1[r] = 0.f; }

    if (t > 0) {
        const char* hbase = hfrag + ((t - 1) & 1) * HF_BUF;
#pragma unroll
        for (int it = 0; it < 16; ++it) {
            const int u  = tid + it * 512;      // 0..8191
            const int s  = u >> 6;              // hl = s>>6, mf = (s>>5)&1, kc = s&31
            const int ln = u & 63;
            Hs[s][ln] = *(const short8v*)(hbase
                        + (size_t)(s >> 6) * HF_HL
                        + (size_t)(2 * mh + ((s >> 5) & 1)) * HF_MT
                        + (size_t)(s & 31) * 1024 + (size_t)ln * 16);
        }
        __syncthreads();

        const char* wb = Wf + (size_t)((g * 64 + ngrp) * 2 + kh) * 16384 + (size_t)l * 16;
#pragma unroll 4
        for (int kcl = 0; kcl < 16; ++kcl) {
            const char* w0 = wb + kcl * 1024;
            const short8v bh = *(const short8v*)(w0);
            const short8v bl = *(const short8v*)(w0 + WF_LO_OFF);
            const int kc = kh * 16 + kcl;
            const short8v ah0 = Hs[kc][l];
            const short8v ah1 = Hs[32 + kc][l];
            const short8v al0 = Hs[64 + kc][l];
            const short8v al1 = Hs[96 + kc][l];
            aA0 = __builtin_amdgcn_mfma_f32_16x16x32_bf16(ah0, bh, aA0, 0, 0, 0);
            aB0 = __builtin_amdgcn_mfma_f32_16x16x32_bf16(al0, bh, aB0, 0, 0, 0);
            aB0 = __builtin_amdgcn_mfma_f32_16x16x32_bf16(ah0, bl, aB0, 0, 0, 0);
            aA1 = __builtin_amdgcn_mfma_f32_16x16x32_bf16(ah1, bh, aA1, 0, 0, 0);
            aB1 = __builtin_amdgcn_mfma_f32_16x16x32_bf16(al1, bh, aB1, 0, 0, 0);
            aB1 = __builtin_amdgcn_mfma_f32_16x16x32_bf16(ah1, bl, aB1, 0, 0, 0);
        }
    }

    // partial gate tiles -> LDS (zeros at t==0); D: col=l&15, row=lhi*4+r
#pragma unroll
    for (int r = 0; r < 4; ++r) {
        gates_s[kh][g][lhi * 4 + r][llo]      = aA0[r] + aB0[r];
        gates_s[kh][g][16 + lhi * 4 + r][llo] = aA1[r] + aB1[r];
    }
    __syncthreads();

    // LSTM cell: 512 threads = 32 rows x 16 cols, one element each
    {
        const int r  = tid >> 4;
        const int cw = tid & 15;
        const int row = mh * 32 + r;
        const int col = ngrp * 16 + cw;
        float gate[4];
#pragma unroll
        for (int gg = 0; gg < 4; ++gg) {
            const size_t gidx = ((size_t)row * 64 + t) * 4096
                              + (size_t)gg * 1024 + col;
            gate[gg] = gates_s[0][gg][r][cw] + gates_s[1][gg][r][cw]
                     + Gx[gidx] + b_hh[gg * 1024 + col];
        }
        float ig = 1.f / (1.f + __expf(-gate[0]));
        float fg = 1.f / (1.f + __expf(-gate[1]));
        float gg = tanhf(gate[2]);
        float og = 1.f / (1.f + __expf(-gate[3]));
        const size_t cidx = (size_t)row * 1024 + col;
        float cp = (t > 0) ? c[cidx] : 0.f;
        float cn = fg * cp + ig * gg;
        float hn = og * tanhf(cn);
        c[cidx] = cn;
        h_s[r][cw] = hn;

        // classifier partial: reduce over 16 cols (cw), then atomicAdd
        float s0 = hn * Wc_s[0][cw];
        float s1 = hn * Wc_s[1][cw];
#pragma unroll
        for (int off = 8; off > 0; off >>= 1) {
            s0 += __shfl_xor(s0, off);
            s1 += __shfl_xor(s1, off);
        }
        if (cw == 0) {
            float* o = out + ((size_t)row * 64 + t) * 2;
            atomicAdd(o,     s0);
            atomicAdd(o + 1, s1);
        }
    }
    __syncthreads();

    // h-fragment write: WG owns kc = ngrp>>1, koct pair (ngrp&1)*2..+1,
    // m_tiles 2mh..2mh+1, hi/lo.  128 threads x 16B chunks.
    if (tid < 128) {
        const int idx16  = tid & 15;
        const int koct_h = (tid >> 4) & 1;
        const int mt_l   = (tid >> 5) & 1;
        const int hl     = tid >> 6;
        const int lane   = idx16 | (((ngrp & 1) * 2 + koct_h) << 4);
        short8v v;
#pragma unroll
        for (int e = 0; e < 8; ++e) {
            float hv = h_s[mt_l * 16 + idx16][koct_h * 8 + e];
            u16 hb_ = f2bf(hv);
            v[e] = (short)(hl == 0 ? hb_ : f2bf(hv - bf2f(hb_)));
        }
        char* dst = hfrag + (t & 1) * HF_BUF + (size_t)hl * HF_HL
                  + (size_t)(2 * mh + mt_l) * HF_MT
                  + (size_t)(ngrp >> 1) * 1024 + (size_t)lane * 16;
        *(short8v*)dst = v;
    }
}

// ---------------------------------------------------------------------------
extern "C" void kernel_launch(void* const* d_in, const int* in_sizes, int n_in,
                              void* d_out, int out_size, void* d_ws, size_t ws_size,
                              hipStream_t stream) {
    const float* x      = (const float*)d_in[0];
    const float* W_feat = (const float*)d_in[1];
    const float* b_feat = (const float*)d_in[2];
    const float* W_ih   = (const float*)d_in[3];
    const float* b_ih   = (const float*)d_in[4];
    const float* W_hh   = (const float*)d_in[5];
    const float* b_hh   = (const float*)d_in[6];
    const float* W_cls  = (const float*)d_in[7];
    const float* b_cls  = (const float*)d_in[8];
    float* out = (float*)d_out;

    char* ws = (char*)d_ws;
    u16*  Fh  = (u16*)ws;                      // [0,16M)  8192x1024 u16
    u16*  Fl  = (u16*)(ws + 16777216);         // [16,32M)
    float* Gx = (float*)(ws + 33554432);       // [32,160M) 8192x4096 f32
    u16*  Wfh = (u16*)(ws + 33554432);         // [32,40M)  1024x4096 u16, dead at B
    u16*  Wfl = (u16*)(ws + 41943040);         // [40,48M)  dead at B
    char* Wf    = ws;                          // [0,16M)  after pack (post-B)
    char* hfrag = ws + 16777216;               // [16,17M) post-B
    float* c    = (float*)(ws + 17825792);     // [17,17.5M) post-B

    // prep: W_feat = 1024x4096 = 4,194,304 floats = 1,048,576 float4 chunks
    split_pair<<<dim3(4096), dim3(256), 0, stream>>>(W_feat, Wfh, Wfl, 1048576);
    out_init<<<dim3(64), dim3(256), 0, stream>>>(out, b_cls);

    // Phase A: Fh/Fl = split(relu(X @ W_feat^T + b_feat))  M=8192 N=1024 K=4096
    gemm_mfma<false, true, true, true>
        <<<dim3(64, 8), 256, 0, stream>>>(
            x, nullptr, nullptr, 4096,
            nullptr, Wfh, Wfl, 4096, b_feat,
            nullptr, Fh, Fl, 1024, 4096);

    // Phase B: Gx = F @ W_ih^T + b_ih   M=8192 N=4096 K=1024
    gemm_mfma<true, false, false, false>
        <<<dim3(64, 32), 256, 0, stream>>>(
            nullptr, Fh, Fl, 1024,
            W_ih, nullptr, nullptr, 1024, b_ih,
            Gx, nullptr, nullptr, 4096, 1024);

    // pack W_hh fragments AFTER phase B (aliases dead Fh region)
    pack_whh2<<<dim3(2048), dim3(256), 0, stream>>>(W_hh, Wf);

    // Phase C: 64 fused recurrent steps (per-step launches; see r10 note)
    for (int t = 0; t < 64; ++t) {
        lstm_step<<<dim3(256), dim3(512), 0, stream>>>(
            Gx, b_hh, Wf, hfrag, c, W_cls, out, t);
    }
}

// Round 12
// 1065.436 us; speedup vs baseline: 4.8201x; 1.0337x over previous
//
#include <hip/hip_runtime.h>
#include <math.h>

// ---------------------------------------------------------------------------
// DiscriminatorLSTM: B=128, T=64, FEAT=4096, FUSION=1024, H=1024, C=2
//
// Split-bf16 (hi/lo) MFMA: v = hi + lo, A*B ~= ah*bh + al*bh + ah*bl
//
// prep:    split_pair: W_feat (1024x4096 = 1,048,576 float4) -> Wfh/Wfl
// Phase A: Fh/Fl = split(relu(X @ W_feat^T + b_feat))
// Phase B: Gx(f32) = F @ W_ih^T + b_ih, stored TIME-MAJOR [t*128+b][4096]
//          so each lstm_step reads one contiguous 2MB block (r12)
// pack_whh2 (AFTER B, aliases Fh region): W_hh -> 16-col B-fragment pack
// Phase C: 64x lstm_step (r9-proven structure)
//
// History: r10 cooperative grid.sync = 4.6x SLOWER (~73us/cross-XCD barrier).
//          r11 XCD block swizzle = WORSE (FETCH 132->532MB; default dispatch
//          order already time-correlates A-panel reads). Both reverted.
//
// ws layout (sizes verified):
//   [0,16M)    Fh (8192x1024 u16) | after B: Wf2 hi [0,8M) lo [8,16M)
//   [16,32M)   Fl                 | after B: hfrag @16M (1MB dbuf), c @17M
//   [32,160M)  Gx f32 (128 MB)    | BEFORE B: Wfh @32M (8MB), Wfl @40M (8MB)
// ---------------------------------------------------------------------------

typedef __attribute__((ext_vector_type(8))) short short8v;   // 8 bf16
typedef __attribute__((ext_vector_type(4))) float f32x4;
typedef unsigned short u16;

#define WF_LO_OFF 8388608u
#define HF_BUF    524288
#define HF_HL     262144
#define HF_MT     32768

__device__ __forceinline__ u16 f2bf(float f) {   // RNE f32->bf16
    unsigned u = __builtin_bit_cast(unsigned, f);
    u = (u + 0x7fffu + ((u >> 16) & 1u)) >> 16;
    return (u16)u;
}
__device__ __forceinline__ float bf2f(u16 b) {
    unsigned u = ((unsigned)b) << 16;
    return __builtin_bit_cast(float, u);
}
__device__ __forceinline__ void split8(const float* f, short8v& hi, short8v& lo) {
#pragma unroll
    for (int e = 0; e < 8; ++e) {
        u16 h = f2bf(f[e]);
        hi[e] = (short)h;
        lo[e] = (short)f2bf(f[e] - bf2f(h));
    }
}

// ---------------- elementwise f32 -> (hi,lo) bf16 split --------------------
__global__ void split_pair(const float* __restrict__ src,
                           u16* __restrict__ dh, u16* __restrict__ dl, int n4) {
    int i = blockIdx.x * blockDim.x + threadIdx.x;
    if (i >= n4) return;
    float4 v = ((const float4*)src)[i];
    float f[4] = {v.x, v.y, v.z, v.w};
    u16 h[4], lo[4];
#pragma unroll
    for (int e = 0; e < 4; ++e) {
        h[e]  = f2bf(f[e]);
        lo[e] = f2bf(f[e] - bf2f(h[e]));
    }
    ((ushort4*)dh)[i] = make_ushort4(h[0], h[1], h[2], h[3]);
    ((ushort4*)dl)[i] = make_ushort4(lo[0], lo[1], lo[2], lo[3]);
}

// ------------------- split-bf16 MFMA GEMM  (C = A @ B^T) -------------------
// Fragment LDS position swizzle: p = (row ^ (koct<<1)) | (koct<<4)  [r9: kills
// the 4-way staging-write conflict, SQ_LDS_BANK_CONFLICT 5e7 -> 0].
// OUT_TMAJOR: output row b*64+t remapped to t*128+b (time-major Gx).
template<bool A_PRESPLIT, bool B_PRESPLIT, bool RELU, bool OUT_SPLIT, bool OUT_TMAJOR>
__global__ __launch_bounds__(256)
void gemm_mfma(const float* __restrict__ Af,
               const u16* __restrict__ Ah, const u16* __restrict__ Al, int lda,
               const float* __restrict__ Bf,
               const u16* __restrict__ Bh, const u16* __restrict__ Bl, int ldb,
               const float* __restrict__ bias,
               float* __restrict__ C, u16* __restrict__ Ch, u16* __restrict__ Cl,
               int ldc, int K)
{
    __shared__ short8v AsH[8][64];
    __shared__ short8v AsL[8][64];
    __shared__ short8v BsH[8][64];
    __shared__ short8v BsL[8][64];

    const int tid = threadIdx.x;
    const int l   = tid & 63;
    const int w   = tid >> 6;
    const int wm  = w & 1, wn = w >> 1;
    const int bm  = blockIdx.x * 128, bn = blockIdx.y * 128;

    const int sm    = tid >> 2;
    const int sk8   = (tid & 3) * 8;
    const int koct_s = sk8 >> 3;
    const int slane = ((sm & 15) ^ (koct_s << 1)) | (koct_s << 4);  // swizzled
    const int smf   = sm >> 4;
    const int lsw   = ((l & 15) ^ ((l >> 4) << 1)) | (l & 48);      // read side

    f32x4 acc[4][4];
#pragma unroll
    for (int i = 0; i < 4; ++i)
#pragma unroll
        for (int j = 0; j < 4; ++j)
#pragma unroll
            for (int r = 0; r < 4; ++r) acc[i][j][r] = 0.f;

    for (int k0 = 0; k0 < K; k0 += 32) {
        if constexpr (A_PRESPLIT) {
            const size_t o0 = (size_t)(bm + sm) * lda + k0 + sk8;
            const size_t o1 = (size_t)(bm + sm + 64) * lda + k0 + sk8;
            AsH[smf][slane]     = *(const short8v*)(Ah + o0);
            AsL[smf][slane]     = *(const short8v*)(Al + o0);
            AsH[smf + 4][slane] = *(const short8v*)(Ah + o1);
            AsL[smf + 4][slane] = *(const short8v*)(Al + o1);
        } else {
            float fa[8], fb[8];
            const float* p0 = Af + (size_t)(bm + sm) * lda + k0 + sk8;
            const float* p1 = Af + (size_t)(bm + sm + 64) * lda + k0 + sk8;
            *(float4*)(fa)     = *(const float4*)(p0);
            *(float4*)(fa + 4) = *(const float4*)(p0 + 4);
            *(float4*)(fb)     = *(const float4*)(p1);
            *(float4*)(fb + 4) = *(const float4*)(p1 + 4);
            short8v hi, lo;
            split8(fa, hi, lo);
            AsH[smf][slane] = hi; AsL[smf][slane] = lo;
            split8(fb, hi, lo);
            AsH[smf + 4][slane] = hi; AsL[smf + 4][slane] = lo;
        }
        if constexpr (B_PRESPLIT) {
            const size_t o0 = (size_t)(bn + sm) * ldb + k0 + sk8;
            const size_t o1 = (size_t)(bn + sm + 64) * ldb + k0 + sk8;
            BsH[smf][slane]     = *(const short8v*)(Bh + o0);
            BsL[smf][slane]     = *(const short8v*)(Bl + o0);
            BsH[smf + 4][slane] = *(const short8v*)(Bh + o1);
            BsL[smf + 4][slane] = *(const short8v*)(Bl + o1);
        } else {
            float fa[8], fb[8];
            const float* p0 = Bf + (size_t)(bn + sm) * ldb + k0 + sk8;
            const float* p1 = Bf + (size_t)(bn + sm + 64) * ldb + k0 + sk8;
            *(float4*)(fa)     = *(const float4*)(p0);
            *(float4*)(fa + 4) = *(const float4*)(p0 + 4);
            *(float4*)(fb)     = *(const float4*)(p1);
            *(float4*)(fb + 4) = *(const float4*)(p1 + 4);
            short8v hi, lo;
            split8(fa, hi, lo);
            BsH[smf][slane] = hi; BsL[smf][slane] = lo;
            split8(fb, hi, lo);
            BsH[smf + 4][slane] = hi; BsL[smf + 4][slane] = lo;
        }
        __syncthreads();

        short8v a_h[4], a_l[4];
#pragma unroll
        for (int i = 0; i < 4; ++i) {
            a_h[i] = AsH[wm * 4 + i][lsw];
            a_l[i] = AsL[wm * 4 + i][lsw];
        }
#pragma unroll
        for (int j = 0; j < 4; ++j) {
            const short8v b_h = BsH[wn * 4 + j][lsw];
            const short8v b_l = BsL[wn * 4 + j][lsw];
#pragma unroll
            for (int i = 0; i < 4; ++i) {
                acc[i][j] = __builtin_amdgcn_mfma_f32_16x16x32_bf16(a_h[i], b_h, acc[i][j], 0, 0, 0);
                acc[i][j] = __builtin_amdgcn_mfma_f32_16x16x32_bf16(a_l[i], b_h, acc[i][j], 0, 0, 0);
                acc[i][j] = __builtin_amdgcn_mfma_f32_16x16x32_bf16(a_h[i], b_l, acc[i][j], 0, 0, 0);
            }
        }
        __syncthreads();
    }

    const int row0 = bm + wm * 64 + (l >> 4) * 4;
    const int col0 = bn + wn * 64 + (l & 15);
#pragma unroll
    for (int i = 0; i < 4; ++i) {
#pragma unroll
        for (int j = 0; j < 4; ++j) {
            const int col = col0 + j * 16;
            const float bs = bias[col];
#pragma unroll
            for (int r = 0; r < 4; ++r) {
                const int row = row0 + i * 16 + r;
                float v = acc[i][j][r] + bs;
                if (RELU) v = fmaxf(v, 0.f);
                if (OUT_SPLIT) {
                    u16 h = f2bf(v);
                    Ch[(size_t)row * ldc + col] = h;
                    Cl[(size_t)row * ldc + col] = f2bf(v - bf2f(h));
                } else if (OUT_TMAJOR) {
                    // row = b*64 + t  ->  time-major index (t*128 + b)
                    const size_t rr = (size_t)(row & 63) * 128 + (row >> 6);
                    C[rr * ldc + col] = v;
                } else {
                    C[(size_t)row * ldc + col] = v;
                }
            }
        }
    }
}

// ----------- W_hh -> 16-col split-bf16 B-fragment pre-pack -----------------
__global__ void pack_whh2(const float* __restrict__ W, char* __restrict__ Wf) {
    int gid = blockIdx.x * blockDim.x + threadIdx.x;   // < 524288
    int l = gid & 63, fid = gid >> 6;                  // fid < 8192
    int kcl = fid & 15, kh = (fid >> 4) & 1, ngrp = (fid >> 5) & 63, g = fid >> 11;
    int n = g * 1024 + ngrp * 16 + (l & 15);
    int k = kh * 512 + kcl * 32 + (l >> 4) * 8;
    const float* src = W + (size_t)n * 1024 + k;
    short8v hi, lo;
#pragma unroll
    for (int e = 0; e < 8; ++e) {
        float v = src[e];
        u16 hb = f2bf(v);
        hi[e] = (short)hb;
        lo[e] = (short)f2bf(v - bf2f(hb));
    }
    size_t off = (size_t)fid * 1024 + (size_t)l * 16;
    *(short8v*)(Wf + off) = hi;
    *(short8v*)(Wf + WF_LO_OFF + off) = lo;
}

__global__ void out_init(float* __restrict__ out, const float* __restrict__ b_cls) {
    int i = blockIdx.x * blockDim.x + threadIdx.x;
    if (i < 16384) out[i] = b_cls[i & 1];
}

// --------------------------- fused LSTM step (r9-proven) -------------------
// 256 WGs x 512 thr. WG (mh = bid>>6, ngrp = bid&63): rows mh*32..+32,
// per-gate cols ngrp*16..+16. Wave w: gate g=w&3, K-half kh=w>>2.
// Gx is TIME-MAJOR: gate slice for step t is the contiguous 2MB block
// Gx[(t*128 + b)*4096 + ...].
__global__ __launch_bounds__(512)
void lstm_step(const float* __restrict__ Gx,
               const float* __restrict__ b_hh,
               const char*  __restrict__ Wf,
               char*        __restrict__ hfrag,
               float*       __restrict__ c,
               const float* __restrict__ Wc,
               float*       __restrict__ out,
               int t)
{
    __shared__ short8v Hs[128][64];          // 128 KB: s = (hl*2+mf)*32 + kc
    __shared__ float gates_s[2][4][32][16];  // 16 KB
    __shared__ float h_s[32][16];            // 2 KB
    __shared__ float Wc_s[2][16];

    const int tid = threadIdx.x, bid = blockIdx.x;
    const int w = tid >> 6, l = tid & 63;
    const int g = w & 3, kh = w >> 2;
    const int ngrp = bid & 63, mh = bid >> 6;

    if (tid < 32) Wc_s[tid >> 4][tid & 15] =
        Wc[(size_t)(tid >> 4) * 1024 + ngrp * 16 + (tid & 15)];

    const int lhi = l >> 4;
    const int llo = l & 15;

    f32x4 aA0, aB0, aA1, aB1;
#pragma unroll
    for (int r = 0; r < 4; ++r) { aA0[r] = 0.f; aB0[r] = 0.f; aA1[r] = 0.f; aB1[r] = 0.f; }

    if (t > 0) {
        const char* hbase = hfrag + ((t - 1) & 1) * HF_BUF;
#pragma unroll
        for (int it = 0; it < 16; ++it) {
            const int u  = tid + it * 512;      // 0..8191
            const int s  = u >> 6;              // hl = s>>6, mf = (s>>5)&1, kc = s&31
            const int ln = u & 63;
            Hs[s][ln] = *(const short8v*)(hbase
                        + (size_t)(s >> 6) * HF_HL
                        + (size_t)(2 * mh + ((s >> 5) & 1)) * HF_MT
                        + (size_t)(s & 31) * 1024 + (size_t)ln * 16);
        }
        __syncthreads();

        const char* wb = Wf + (size_t)((g * 64 + ngrp) * 2 + kh) * 16384 + (size_t)l * 16;
#pragma unroll 4
        for (int kcl = 0; kcl < 16; ++kcl) {
            const char* w0 = wb + kcl * 1024;
            const short8v bh = *(const short8v*)(w0);
            const short8v bl = *(const short8v*)(w0 + WF_LO_OFF);
            const int kc = kh * 16 + kcl;
            const short8v ah0 = Hs[kc][l];
            const short8v ah1 = Hs[32 + kc][l];
            const short8v al0 = Hs[64 + kc][l];
            const short8v al1 = Hs[96 + kc][l];
            aA0 = __builtin_amdgcn_mfma_f32_16x16x32_bf16(ah0, bh, aA0, 0, 0, 0);
            aB0 = __builtin_amdgcn_mfma_f32_16x16x32_bf16(al0, bh, aB0, 0, 0, 0);
            aB0 = __builtin_amdgcn_mfma_f32_16x16x32_bf16(ah0, bl, aB0, 0, 0, 0);
            aA1 = __builtin_amdgcn_mfma_f32_16x16x32_bf16(ah1, bh, aA1, 0, 0, 0);
            aB1 = __builtin_amdgcn_mfma_f32_16x16x32_bf16(al1, bh, aB1, 0, 0, 0);
            aB1 = __builtin_amdgcn_mfma_f32_16x16x32_bf16(ah1, bl, aB1, 0, 0, 0);
        }
    }

    // partial gate tiles -> LDS (zeros at t==0); D: col=l&15, row=lhi*4+r
#pragma unroll
    for (int r = 0; r < 4; ++r) {
        gates_s[kh][g][lhi * 4 + r][llo]      = aA0[r] + aB0[r];
        gates_s[kh][g][16 + lhi * 4 + r][llo] = aA1[r] + aB1[r];
    }
    __syncthreads();

    // LSTM cell: 512 threads = 32 rows x 16 cols, one element each
    {
        const int r  = tid >> 4;
        const int cw = tid & 15;
        const int row = mh * 32 + r;
        const int col = ngrp * 16 + cw;
        float gate[4];
#pragma unroll
        for (int gg = 0; gg < 4; ++gg) {
            const size_t gidx = ((size_t)t * 128 + row) * 4096
                              + (size_t)gg * 1024 + col;
            gate[gg] = gates_s[0][gg][r][cw] + gates_s[1][gg][r][cw]
                     + Gx[gidx] + b_hh[gg * 1024 + col];
        }
        float ig = 1.f / (1.f + __expf(-gate[0]));
        float fg = 1.f / (1.f + __expf(-gate[1]));
        float gg = tanhf(gate[2]);
        float og = 1.f / (1.f + __expf(-gate[3]));
        const size_t cidx = (size_t)row * 1024 + col;
        float cp = (t > 0) ? c[cidx] : 0.f;
        float cn = fg * cp + ig * gg;
        float hn = og * tanhf(cn);
        c[cidx] = cn;
        h_s[r][cw] = hn;

        // classifier partial: reduce over 16 cols (cw), then atomicAdd
        float s0 = hn * Wc_s[0][cw];
        float s1 = hn * Wc_s[1][cw];
#pragma unroll
        for (int off = 8; off > 0; off >>= 1) {
            s0 += __shfl_xor(s0, off);
            s1 += __shfl_xor(s1, off);
        }
        if (cw == 0) {
            float* o = out + ((size_t)row * 64 + t) * 2;
            atomicAdd(o,     s0);
            atomicAdd(o + 1, s1);
        }
    }
    __syncthreads();

    // h-fragment write: WG owns kc = ngrp>>1, koct pair (ngrp&1)*2..+1,
    // m_tiles 2mh..2mh+1, hi/lo.  128 threads x 16B chunks.
    if (tid < 128) {
        const int idx16  = tid & 15;
        const int koct_h = (tid >> 4) & 1;
        const int mt_l   = (tid >> 5) & 1;
        const int hl     = tid >> 6;
        const int lane   = idx16 | (((ngrp & 1) * 2 + koct_h) << 4);
        short8v v;
#pragma unroll
        for (int e = 0; e < 8; ++e) {
            float hv = h_s[mt_l * 16 + idx16][koct_h * 8 + e];
            u16 hb_ = f2bf(hv);
            v[e] = (short)(hl == 0 ? hb_ : f2bf(hv - bf2f(hb_)));
        }
        char* dst = hfrag + (t & 1) * HF_BUF + (size_t)hl * HF_HL
                  + (size_t)(2 * mh + mt_l) * HF_MT
                  + (size_t)(ngrp >> 1) * 1024 + (size_t)lane * 16;
        *(short8v*)dst = v;
    }
}

// ---------------------------------------------------------------------------
extern "C" void kernel_launch(void* const* d_in, const int* in_sizes, int n_in,
                              void* d_out, int out_size, void* d_ws, size_t ws_size,
                              hipStream_t stream) {
    const float* x      = (const float*)d_in[0];
    const float* W_feat = (const float*)d_in[1];
    const float* b_feat = (const float*)d_in[2];
    const float* W_ih   = (const float*)d_in[3];
    const float* b_ih   = (const float*)d_in[4];
    const float* W_hh   = (const float*)d_in[5];
    const float* b_hh   = (const float*)d_in[6];
    const float* W_cls  = (const float*)d_in[7];
    const float* b_cls  = (const float*)d_in[8];
    float* out = (float*)d_out;

    char* ws = (char*)d_ws;
    u16*  Fh  = (u16*)ws;                      // [0,16M)  8192x1024 u16
    u16*  Fl  = (u16*)(ws + 16777216);         // [16,32M)
    float* Gx = (float*)(ws + 33554432);       // [32,160M) 8192x4096 f32, TIME-MAJOR
    u16*  Wfh = (u16*)(ws + 33554432);         // [32,40M)  1024x4096 u16, dead at B
    u16*  Wfl = (u16*)(ws + 41943040);         // [40,48M)  dead at B
    char* Wf    = ws;                          // [0,16M)  after pack (post-B)
    char* hfrag = ws + 16777216;               // [16,17M) post-B
    float* c    = (float*)(ws + 17825792);     // [17,17.5M) post-B

    // prep: W_feat = 1024x4096 = 4,194,304 floats = 1,048,576 float4 chunks
    split_pair<<<dim3(4096), dim3(256), 0, stream>>>(W_feat, Wfh, Wfl, 1048576);
    out_init<<<dim3(64), dim3(256), 0, stream>>>(out, b_cls);

    // Phase A: Fh/Fl = split(relu(X @ W_feat^T + b_feat))  M=8192 N=1024 K=4096
    gemm_mfma<false, true, true, true, false>
        <<<dim3(64, 8), 256, 0, stream>>>(
            x, nullptr, nullptr, 4096,
            nullptr, Wfh, Wfl, 4096, b_feat,
            nullptr, Fh, Fl, 1024, 4096);

    // Phase B: Gx = F @ W_ih^T + b_ih   M=8192 N=4096 K=1024, time-major out
    gemm_mfma<true, false, false, false, true>
        <<<dim3(64, 32), 256, 0, stream>>>(
            nullptr, Fh, Fl, 1024,
            W_ih, nullptr, nullptr, 1024, b_ih,
            Gx, nullptr, nullptr, 4096, 1024);

    // pack W_hh fragments AFTER phase B (aliases dead Fh region)
    pack_whh2<<<dim3(2048), dim3(256), 0, stream>>>(W_hh, Wf);

    // Phase C: 64 fused recurrent steps (per-step launches; see r10 note)
    for (int t = 0; t < 64; ++t) {
        lstm_step<<<dim3(256), dim3(512), 0, stream>>>(
            Gx, b_hh, Wf, hfrag, c, W_cls, out, t);
    }
}

// Round 13
// 831.075 us; speedup vs baseline: 6.1793x; 1.2820x over previous
//
#include <hip/hip_runtime.h>
#include <math.h>

// ---------------------------------------------------------------------------
// DiscriminatorLSTM: B=128, T=64, FEAT=4096, FUSION=1024, H=1024, C=2
//
// r13: phases A/B use SINGLE-PRODUCT f16 MFMA (mfma_f32_16x16x32_f16).
//   Error budget: gate err ~5e-4 std (f16 operand quant, fp32 accum, K<=4096
//   with small per-term products) -> absmax est 4-7e-3 vs 12.5e-3 threshold.
//   Phase C recurrence stays split-bf16 (proven, compounding loop untouched).
//
// prep:    cvt_f16: W_feat -> Wf16, W_ih -> Wih16 (u16 f16)
// Phase A: F16 = f16(relu(X @ W_feat^T + b_feat))   (A-side X f32->f16 on fly)
// Phase B: Gx(f32) = F16 @ Wih16^T + b_ih, TIME-MAJOR [t*128+b][4096]
// pack_whh2 (AFTER B, aliases F16): W_hh -> 16-col split-bf16 B-frag pack
// Phase C: 64x lstm_step (r9-proven, split-bf16)
//
// History: r10 grid.sync 4.6x slower; r11 XCD swizzle worse (both reverted).
//
// ws layout (sizes verified, peak 160 MB):
//   [0,16M)   F16 (8192x1024 u16)      | after B: Wf pack hi [0,8M) lo [8,16M)
//   [16,24M)  Wih16 (4096x1024 u16)    | after B: hfrag @16M (1MB), c @17MB
//   [24,32M)  Wf16 (1024x4096 u16)     | dead after phase A
//   [32,160M) Gx f32 (128 MB, time-major)
// ---------------------------------------------------------------------------

typedef __attribute__((ext_vector_type(8))) short short8v;   // 8 x 16-bit
typedef __attribute__((ext_vector_type(4))) float f32x4;
typedef unsigned short u16;

#define WF_LO_OFF 8388608u
#define HF_BUF    524288
#define HF_HL     262144
#define HF_MT     32768

__device__ __forceinline__ u16 f2bf(float f) {   // RNE f32->bf16
    unsigned u = __builtin_bit_cast(unsigned, f);
    u = (u + 0x7fffu + ((u >> 16) & 1u)) >> 16;
    return (u16)u;
}
__device__ __forceinline__ float bf2f(u16 b) {
    unsigned u = ((unsigned)b) << 16;
    return __builtin_bit_cast(float, u);
}
__device__ __forceinline__ short f2h(float f) {  // RNE f32->f16 (v_cvt_f16_f32)
    return __builtin_bit_cast(short, (_Float16)f);
}

// ---------------- elementwise f32 -> f16 convert ---------------------------
__global__ void cvt_f16(const float* __restrict__ src, u16* __restrict__ d, int n4) {
    int i = blockIdx.x * blockDim.x + threadIdx.x;
    if (i >= n4) return;
    float4 v = ((const float4*)src)[i];
    ushort4 o;
    o.x = (u16)f2h(v.x); o.y = (u16)f2h(v.y);
    o.z = (u16)f2h(v.z); o.w = (u16)f2h(v.w);
    ((ushort4*)d)[i] = o;
}

// ------------------- f16 MFMA GEMM  (C = A @ B^T) --------------------------
// B-side always pre-converted f16 (u16). A-side: f32 (cvt on fly) or pre-f16.
// 128x128 tile, BK=32, 4 waves. LDS fragment swizzle p=(row^(koct<<1))|(koct<<4)
// [r9-proven conflict-free]. OUT_TMAJOR: row b*64+t -> t*128+b.
template<bool A_PRE16, bool RELU, bool OUT_F16, bool OUT_TMAJOR>
__global__ __launch_bounds__(256)
void gemm_f16(const float* __restrict__ Af,
              const u16* __restrict__ A16, int lda,
              const u16* __restrict__ B16, int ldb,
              const float* __restrict__ bias,
              float* __restrict__ C, u16* __restrict__ C16,
              int ldc, int K)
{
    __shared__ short8v As[8][64];
    __shared__ short8v Bs[8][64];

    const int tid = threadIdx.x;
    const int l   = tid & 63;
    const int w   = tid >> 6;
    const int wm  = w & 1, wn = w >> 1;
    const int bm  = blockIdx.x * 128, bn = blockIdx.y * 128;

    const int sm    = tid >> 2;
    const int sk8   = (tid & 3) * 8;
    const int koct_s = sk8 >> 3;
    const int slane = ((sm & 15) ^ (koct_s << 1)) | (koct_s << 4);  // swizzled
    const int smf   = sm >> 4;
    const int lsw   = ((l & 15) ^ ((l >> 4) << 1)) | (l & 48);      // read side

    f32x4 acc[4][4];
#pragma unroll
    for (int i = 0; i < 4; ++i)
#pragma unroll
        for (int j = 0; j < 4; ++j)
#pragma unroll
            for (int r = 0; r < 4; ++r) acc[i][j][r] = 0.f;

    for (int k0 = 0; k0 < K; k0 += 32) {
        // ---- stage A tile ----
        if constexpr (A_PRE16) {
            const size_t o0 = (size_t)(bm + sm) * lda + k0 + sk8;
            const size_t o1 = (size_t)(bm + sm + 64) * lda + k0 + sk8;
            As[smf][slane]     = *(const short8v*)(A16 + o0);
            As[smf + 4][slane] = *(const short8v*)(A16 + o1);
        } else {
            float fa[8], fb[8];
            const float* p0 = Af + (size_t)(bm + sm) * lda + k0 + sk8;
            const float* p1 = Af + (size_t)(bm + sm + 64) * lda + k0 + sk8;
            *(float4*)(fa)     = *(const float4*)(p0);
            *(float4*)(fa + 4) = *(const float4*)(p0 + 4);
            *(float4*)(fb)     = *(const float4*)(p1);
            *(float4*)(fb + 4) = *(const float4*)(p1 + 4);
            short8v ha, hb;
#pragma unroll
            for (int e = 0; e < 8; ++e) { ha[e] = f2h(fa[e]); hb[e] = f2h(fb[e]); }
            As[smf][slane]     = ha;
            As[smf + 4][slane] = hb;
        }
        // ---- stage B tile (always pre-f16) ----
        {
            const size_t o0 = (size_t)(bn + sm) * ldb + k0 + sk8;
            const size_t o1 = (size_t)(bn + sm + 64) * ldb + k0 + sk8;
            Bs[smf][slane]     = *(const short8v*)(B16 + o0);
            Bs[smf + 4][slane] = *(const short8v*)(B16 + o1);
        }
        __syncthreads();

        short8v a[4];
#pragma unroll
        for (int i = 0; i < 4; ++i) a[i] = As[wm * 4 + i][lsw];
#pragma unroll
        for (int j = 0; j < 4; ++j) {
            const short8v b = Bs[wn * 4 + j][lsw];
#pragma unroll
            for (int i = 0; i < 4; ++i)
                acc[i][j] = __builtin_amdgcn_mfma_f32_16x16x32_f16(a[i], b, acc[i][j], 0, 0, 0);
        }
        __syncthreads();
    }

    const int row0 = bm + wm * 64 + (l >> 4) * 4;
    const int col0 = bn + wn * 64 + (l & 15);
#pragma unroll
    for (int i = 0; i < 4; ++i) {
#pragma unroll
        for (int j = 0; j < 4; ++j) {
            const int col = col0 + j * 16;
            const float bs = bias[col];
#pragma unroll
            for (int r = 0; r < 4; ++r) {
                const int row = row0 + i * 16 + r;
                float v = acc[i][j][r] + bs;
                if (RELU) v = fmaxf(v, 0.f);
                if (OUT_F16) {
                    C16[(size_t)row * ldc + col] = (u16)f2h(v);
                } else if (OUT_TMAJOR) {
                    // row = b*64 + t  ->  time-major index (t*128 + b)
                    const size_t rr = (size_t)(row & 63) * 128 + (row >> 6);
                    C[rr * ldc + col] = v;
                } else {
                    C[(size_t)row * ldc + col] = v;
                }
            }
        }
    }
}

// ----------- W_hh -> 16-col split-bf16 B-fragment pre-pack -----------------
__global__ void pack_whh2(const float* __restrict__ W, char* __restrict__ Wf) {
    int gid = blockIdx.x * blockDim.x + threadIdx.x;   // < 524288
    int l = gid & 63, fid = gid >> 6;                  // fid < 8192
    int kcl = fid & 15, kh = (fid >> 4) & 1, ngrp = (fid >> 5) & 63, g = fid >> 11;
    int n = g * 1024 + ngrp * 16 + (l & 15);
    int k = kh * 512 + kcl * 32 + (l >> 4) * 8;
    const float* src = W + (size_t)n * 1024 + k;
    short8v hi, lo;
#pragma unroll
    for (int e = 0; e < 8; ++e) {
        float v = src[e];
        u16 hb = f2bf(v);
        hi[e] = (short)hb;
        lo[e] = (short)f2bf(v - bf2f(hb));
    }
    size_t off = (size_t)fid * 1024 + (size_t)l * 16;
    *(short8v*)(Wf + off) = hi;
    *(short8v*)(Wf + WF_LO_OFF + off) = lo;
}

__global__ void out_init(float* __restrict__ out, const float* __restrict__ b_cls) {
    int i = blockIdx.x * blockDim.x + threadIdx.x;
    if (i < 16384) out[i] = b_cls[i & 1];
}

// --------------------------- fused LSTM step (r9-proven) -------------------
// 256 WGs x 512 thr. WG (mh = bid>>6, ngrp = bid&63): rows mh*32..+32,
// per-gate cols ngrp*16..+16. Wave w: gate g=w&3, K-half kh=w>>2.
// Gx TIME-MAJOR: step-t slice = contiguous 2MB block Gx[(t*128+b)*4096+..].
__global__ __launch_bounds__(512)
void lstm_step(const float* __restrict__ Gx,
               const float* __restrict__ b_hh,
               const char*  __restrict__ Wf,
               char*        __restrict__ hfrag,
               float*       __restrict__ c,
               const float* __restrict__ Wc,
               float*       __restrict__ out,
               int t)
{
    __shared__ short8v Hs[128][64];          // 128 KB: s = (hl*2+mf)*32 + kc
    __shared__ float gates_s[2][4][32][16];  // 16 KB
    __shared__ float h_s[32][16];            // 2 KB
    __shared__ float Wc_s[2][16];

    const int tid = threadIdx.x, bid = blockIdx.x;
    const int w = tid >> 6, l = tid & 63;
    const int g = w & 3, kh = w >> 2;
    const int ngrp = bid & 63, mh = bid >> 6;

    if (tid < 32) Wc_s[tid >> 4][tid & 15] =
        Wc[(size_t)(tid >> 4) * 1024 + ngrp * 16 + (tid & 15)];

    const int lhi = l >> 4;
    const int llo = l & 15;

    f32x4 aA0, aB0, aA1, aB1;
#pragma unroll
    for (int r = 0; r < 4; ++r) { aA0[r] = 0.f; aB0[r] = 0.f; aA1[r] = 0.f; aB1[r] = 0.f; }

    if (t > 0) {
        const char* hbase = hfrag + ((t - 1) & 1) * HF_BUF;
#pragma unroll
        for (int it = 0; it < 16; ++it) {
            const int u  = tid + it * 512;      // 0..8191
            const int s  = u >> 6;              // hl = s>>6, mf = (s>>5)&1, kc = s&31
            const int ln = u & 63;
            Hs[s][ln] = *(const short8v*)(hbase
                        + (size_t)(s >> 6) * HF_HL
                        + (size_t)(2 * mh + ((s >> 5) & 1)) * HF_MT
                        + (size_t)(s & 31) * 1024 + (size_t)ln * 16);
        }
        __syncthreads();

        const char* wb = Wf + (size_t)((g * 64 + ngrp) * 2 + kh) * 16384 + (size_t)l * 16;
#pragma unroll 4
        for (int kcl = 0; kcl < 16; ++kcl) {
            const char* w0 = wb + kcl * 1024;
            const short8v bh = *(const short8v*)(w0);
            const short8v bl = *(const short8v*)(w0 + WF_LO_OFF);
            const int kc = kh * 16 + kcl;
            const short8v ah0 = Hs[kc][l];
            const short8v ah1 = Hs[32 + kc][l];
            const short8v al0 = Hs[64 + kc][l];
            const short8v al1 = Hs[96 + kc][l];
            aA0 = __builtin_amdgcn_mfma_f32_16x16x32_bf16(ah0, bh, aA0, 0, 0, 0);
            aB0 = __builtin_amdgcn_mfma_f32_16x16x32_bf16(al0, bh, aB0, 0, 0, 0);
            aB0 = __builtin_amdgcn_mfma_f32_16x16x32_bf16(ah0, bl, aB0, 0, 0, 0);
            aA1 = __builtin_amdgcn_mfma_f32_16x16x32_bf16(ah1, bh, aA1, 0, 0, 0);
            aB1 = __builtin_amdgcn_mfma_f32_16x16x32_bf16(al1, bh, aB1, 0, 0, 0);
            aB1 = __builtin_amdgcn_mfma_f32_16x16x32_bf16(ah1, bl, aB1, 0, 0, 0);
        }
    }

    // partial gate tiles -> LDS (zeros at t==0); D: col=l&15, row=lhi*4+r
#pragma unroll
    for (int r = 0; r < 4; ++r) {
        gates_s[kh][g][lhi * 4 + r][llo]      = aA0[r] + aB0[r];
        gates_s[kh][g][16 + lhi * 4 + r][llo] = aA1[r] + aB1[r];
    }
    __syncthreads();

    // LSTM cell: 512 threads = 32 rows x 16 cols, one element each
    {
        const int r  = tid >> 4;
        const int cw = tid & 15;
        const int row = mh * 32 + r;
        const int col = ngrp * 16 + cw;
        float gate[4];
#pragma unroll
        for (int gg = 0; gg < 4; ++gg) {
            const size_t gidx = ((size_t)t * 128 + row) * 4096
                              + (size_t)gg * 1024 + col;
            gate[gg] = gates_s[0][gg][r][cw] + gates_s[1][gg][r][cw]
                     + Gx[gidx] + b_hh[gg * 1024 + col];
        }
        float ig = 1.f / (1.f + __expf(-gate[0]));
        float fg = 1.f / (1.f + __expf(-gate[1]));
        float gg = tanhf(gate[2]);
        float og = 1.f / (1.f + __expf(-gate[3]));
        const size_t cidx = (size_t)row * 1024 + col;
        float cp = (t > 0) ? c[cidx] : 0.f;
        float cn = fg * cp + ig * gg;
        float hn = og * tanhf(cn);
        c[cidx] = cn;
        h_s[r][cw] = hn;

        // classifier partial: reduce over 16 cols (cw), then atomicAdd
        float s0 = hn * Wc_s[0][cw];
        float s1 = hn * Wc_s[1][cw];
#pragma unroll
        for (int off = 8; off > 0; off >>= 1) {
            s0 += __shfl_xor(s0, off);
            s1 += __shfl_xor(s1, off);
        }
        if (cw == 0) {
            float* o = out + ((size_t)row * 64 + t) * 2;
            atomicAdd(o,     s0);
            atomicAdd(o + 1, s1);
        }
    }
    __syncthreads();

    // h-fragment write: WG owns kc = ngrp>>1, koct pair (ngrp&1)*2..+1,
    // m_tiles 2mh..2mh+1, hi/lo.  128 threads x 16B chunks.
    if (tid < 128) {
        const int idx16  = tid & 15;
        const int koct_h = (tid >> 4) & 1;
        const int mt_l   = (tid >> 5) & 1;
        const int hl     = tid >> 6;
        const int lane   = idx16 | (((ngrp & 1) * 2 + koct_h) << 4);
        short8v v;
#pragma unroll
        for (int e = 0; e < 8; ++e) {
            float hv = h_s[mt_l * 16 + idx16][koct_h * 8 + e];
            u16 hb_ = f2bf(hv);
            v[e] = (short)(hl == 0 ? hb_ : f2bf(hv - bf2f(hb_)));
        }
        char* dst = hfrag + (t & 1) * HF_BUF + (size_t)hl * HF_HL
                  + (size_t)(2 * mh + mt_l) * HF_MT
                  + (size_t)(ngrp >> 1) * 1024 + (size_t)lane * 16;
        *(short8v*)dst = v;
    }
}

// ---------------------------------------------------------------------------
extern "C" void kernel_launch(void* const* d_in, const int* in_sizes, int n_in,
                              void* d_out, int out_size, void* d_ws, size_t ws_size,
                              hipStream_t stream) {
    const float* x      = (const float*)d_in[0];
    const float* W_feat = (const float*)d_in[1];
    const float* b_feat = (const float*)d_in[2];
    const float* W_ih   = (const float*)d_in[3];
    const float* b_ih   = (const float*)d_in[4];
    const float* W_hh   = (const float*)d_in[5];
    const float* b_hh   = (const float*)d_in[6];
    const float* W_cls  = (const float*)d_in[7];
    const float* b_cls  = (const float*)d_in[8];
    float* out = (float*)d_out;

    char* ws = (char*)d_ws;
    u16*  F16   = (u16*)ws;                    // [0,16M)  8192x1024 u16 f16
    u16*  Wih16 = (u16*)(ws + 16777216);       // [16,24M) 4096x1024 u16 f16
    u16*  Wf16  = (u16*)(ws + 25165824);       // [24,32M) 1024x4096 u16 f16
    float* Gx   = (float*)(ws + 33554432);     // [32,160M) f32, TIME-MAJOR
    char* Wf    = ws;                          // [0,16M)  whh pack (post-B)
    char* hfrag = ws + 16777216;               // [16,17M) post-B
    float* c    = (float*)(ws + 17825792);     // [17,17.5M) post-B

    // prep: both weight matrices are 4,194,304 floats = 1,048,576 float4
    cvt_f16<<<dim3(4096), dim3(256), 0, stream>>>(W_feat, Wf16, 1048576);
    cvt_f16<<<dim3(4096), dim3(256), 0, stream>>>(W_ih, Wih16, 1048576);
    out_init<<<dim3(64), dim3(256), 0, stream>>>(out, b_cls);

    // Phase A: F16 = f16(relu(X @ W_feat^T + b_feat))  M=8192 N=1024 K=4096
    gemm_f16<false, true, true, false>
        <<<dim3(64, 8), 256, 0, stream>>>(
            x, nullptr, 4096, Wf16, 4096, b_feat,
            nullptr, F16, 1024, 4096);

    // Phase B: Gx = F16 @ Wih16^T + b_ih   M=8192 N=4096 K=1024, time-major
    gemm_f16<true, false, false, true>
        <<<dim3(64, 32), 256, 0, stream>>>(
            nullptr, F16, 1024, Wih16, 1024, b_ih,
            Gx, nullptr, 4096, 1024);

    // pack W_hh fragments AFTER phase B (aliases dead F16 region)
    pack_whh2<<<dim3(2048), dim3(256), 0, stream>>>(W_hh, Wf);

    // Phase C: 64 fused recurrent steps (per-step launches; see r10 note)
    for (int t = 0; t < 64; ++t) {
        lstm_step<<<dim3(256), dim3(512), 0, stream>>>(
            Gx, b_hh, Wf, hfrag, c, W_cls, out, t);
    }
}

// Round 14
// 711.815 us; speedup vs baseline: 7.2147x; 1.1675x over previous
//
#include <hip/hip_runtime.h>
#include <math.h>

// ---------------------------------------------------------------------------
// DiscriminatorLSTM: B=128, T=64, FEAT=4096, FUSION=1024, H=1024, C=2
//
// r13: phases A/B single-product f16 MFMA (validated: absmax unchanged 2e-3).
// r14: phase C recurrence ALSO single-product f16 (W_hh f16 pack 8MB,
//      h fragments f16, MFMA/wave 96->32, W stream halved).
//      Error budget: ~3e-4/step gate err, sqrt(64)-walk on c -> +~1e-3 absmax.
//
// prep:    cvt_f16: W_feat -> Wf16, W_ih -> Wih16 (u16 f16)
// Phase A: F16 = f16(relu(X @ W_feat^T + b_feat))
// Phase B: Gx(f32) = F16 @ Wih16^T + b_ih, TIME-MAJOR [t*128+b][4096]
// pack_whh3 (AFTER B, aliases F16 region): W_hh -> 16-col f16 B-frag pack
// Phase C: 64x lstm_step (f16 single-product)
//
// History: r10 grid.sync 4.6x slower; r11 XCD swizzle worse (both reverted).
//
// ws layout (sizes verified, peak 160 MB):
//   [0,16M)   F16 (8192x1024 u16)      | after B: Wf f16 pack [0,8M)
//   [16,24M)  Wih16 (4096x1024 u16)    | after B: hfrag @16M (512K dbuf), c @17M
//   [24,32M)  Wf16 (1024x4096 u16)     | dead after phase A
//   [32,160M) Gx f32 (128 MB, time-major)
// ---------------------------------------------------------------------------

typedef __attribute__((ext_vector_type(8))) short short8v;   // 8 x 16-bit
typedef __attribute__((ext_vector_type(4))) float f32x4;
typedef unsigned short u16;

#define HF2_BUF 262144   // one h-frag buffer: 8 mt x 32 kc x 64 lanes x 16B
#define HF2_MT  32768    // per m-tile: 32 kc x 1 KB

__device__ __forceinline__ u16 f2bf(float f) {   // RNE f32->bf16 (unused paths)
    unsigned u = __builtin_bit_cast(unsigned, f);
    u = (u + 0x7fffu + ((u >> 16) & 1u)) >> 16;
    return (u16)u;
}
__device__ __forceinline__ short f2h(float f) {  // RNE f32->f16
    return __builtin_bit_cast(short, (_Float16)f);
}

// ---------------- elementwise f32 -> f16 convert ---------------------------
__global__ void cvt_f16(const float* __restrict__ src, u16* __restrict__ d, int n4) {
    int i = blockIdx.x * blockDim.x + threadIdx.x;
    if (i >= n4) return;
    float4 v = ((const float4*)src)[i];
    ushort4 o;
    o.x = (u16)f2h(v.x); o.y = (u16)f2h(v.y);
    o.z = (u16)f2h(v.z); o.w = (u16)f2h(v.w);
    ((ushort4*)d)[i] = o;
}

// ------------------- f16 MFMA GEMM  (C = A @ B^T) --------------------------
// 128x128 tile, BK=32, 4 waves. LDS fragment swizzle p=(row^(koct<<1))|(koct<<4)
// [r9-proven conflict-free]. OUT_TMAJOR: row b*64+t -> t*128+b.
template<bool A_PRE16, bool RELU, bool OUT_F16, bool OUT_TMAJOR>
__global__ __launch_bounds__(256)
void gemm_f16(const float* __restrict__ Af,
              const u16* __restrict__ A16, int lda,
              const u16* __restrict__ B16, int ldb,
              const float* __restrict__ bias,
              float* __restrict__ C, u16* __restrict__ C16,
              int ldc, int K)
{
    __shared__ short8v As[8][64];
    __shared__ short8v Bs[8][64];

    const int tid = threadIdx.x;
    const int l   = tid & 63;
    const int w   = tid >> 6;
    const int wm  = w & 1, wn = w >> 1;
    const int bm  = blockIdx.x * 128, bn = blockIdx.y * 128;

    const int sm    = tid >> 2;
    const int sk8   = (tid & 3) * 8;
    const int koct_s = sk8 >> 3;
    const int slane = ((sm & 15) ^ (koct_s << 1)) | (koct_s << 4);  // swizzled
    const int smf   = sm >> 4;
    const int lsw   = ((l & 15) ^ ((l >> 4) << 1)) | (l & 48);      // read side

    f32x4 acc[4][4];
#pragma unroll
    for (int i = 0; i < 4; ++i)
#pragma unroll
        for (int j = 0; j < 4; ++j)
#pragma unroll
            for (int r = 0; r < 4; ++r) acc[i][j][r] = 0.f;

    for (int k0 = 0; k0 < K; k0 += 32) {
        if constexpr (A_PRE16) {
            const size_t o0 = (size_t)(bm + sm) * lda + k0 + sk8;
            const size_t o1 = (size_t)(bm + sm + 64) * lda + k0 + sk8;
            As[smf][slane]     = *(const short8v*)(A16 + o0);
            As[smf + 4][slane] = *(const short8v*)(A16 + o1);
        } else {
            float fa[8], fb[8];
            const float* p0 = Af + (size_t)(bm + sm) * lda + k0 + sk8;
            const float* p1 = Af + (size_t)(bm + sm + 64) * lda + k0 + sk8;
            *(float4*)(fa)     = *(const float4*)(p0);
            *(float4*)(fa + 4) = *(const float4*)(p0 + 4);
            *(float4*)(fb)     = *(const float4*)(p1);
            *(float4*)(fb + 4) = *(const float4*)(p1 + 4);
            short8v ha, hb;
#pragma unroll
            for (int e = 0; e < 8; ++e) { ha[e] = f2h(fa[e]); hb[e] = f2h(fb[e]); }
            As[smf][slane]     = ha;
            As[smf + 4][slane] = hb;
        }
        {
            const size_t o0 = (size_t)(bn + sm) * ldb + k0 + sk8;
            const size_t o1 = (size_t)(bn + sm + 64) * ldb + k0 + sk8;
            Bs[smf][slane]     = *(const short8v*)(B16 + o0);
            Bs[smf + 4][slane] = *(const short8v*)(B16 + o1);
        }
        __syncthreads();

        short8v a[4];
#pragma unroll
        for (int i = 0; i < 4; ++i) a[i] = As[wm * 4 + i][lsw];
#pragma unroll
        for (int j = 0; j < 4; ++j) {
            const short8v b = Bs[wn * 4 + j][lsw];
#pragma unroll
            for (int i = 0; i < 4; ++i)
                acc[i][j] = __builtin_amdgcn_mfma_f32_16x16x32_f16(a[i], b, acc[i][j], 0, 0, 0);
        }
        __syncthreads();
    }

    const int row0 = bm + wm * 64 + (l >> 4) * 4;
    const int col0 = bn + wn * 64 + (l & 15);
#pragma unroll
    for (int i = 0; i < 4; ++i) {
#pragma unroll
        for (int j = 0; j < 4; ++j) {
            const int col = col0 + j * 16;
            const float bs = bias[col];
#pragma unroll
            for (int r = 0; r < 4; ++r) {
                const int row = row0 + i * 16 + r;
                float v = acc[i][j][r] + bs;
                if (RELU) v = fmaxf(v, 0.f);
                if (OUT_F16) {
                    C16[(size_t)row * ldc + col] = (u16)f2h(v);
                } else if (OUT_TMAJOR) {
                    const size_t rr = (size_t)(row & 63) * 128 + (row >> 6);
                    C[rr * ldc + col] = v;
                } else {
                    C[(size_t)row * ldc + col] = v;
                }
            }
        }
    }
}

// ----------- W_hh -> 16-col f16 B-fragment pre-pack (8 MB) -----------------
// fid = g*2048 + ngrp*32 + kh*16 + kcl ; lane l: n = g*1024+ngrp*16+(l&15),
// k = kh*512 + kcl*32 + (l>>4)*8 + e
__global__ void pack_whh3(const float* __restrict__ W, char* __restrict__ Wf) {
    int gid = blockIdx.x * blockDim.x + threadIdx.x;   // < 524288
    int l = gid & 63, fid = gid >> 6;                  // fid < 8192
    int kcl = fid & 15, kh = (fid >> 4) & 1, ngrp = (fid >> 5) & 63, g = fid >> 11;
    int n = g * 1024 + ngrp * 16 + (l & 15);
    int k = kh * 512 + kcl * 32 + (l >> 4) * 8;
    const float* src = W + (size_t)n * 1024 + k;
    short8v v16;
#pragma unroll
    for (int e = 0; e < 8; ++e) v16[e] = f2h(src[e]);
    *(short8v*)(Wf + (size_t)fid * 1024 + (size_t)l * 16) = v16;
}

__global__ void out_init(float* __restrict__ out, const float* __restrict__ b_cls) {
    int i = blockIdx.x * blockDim.x + threadIdx.x;
    if (i < 16384) out[i] = b_cls[i & 1];
}

// --------------------------- fused LSTM step (f16) -------------------------
// 256 WGs x 512 thr. WG (mh = bid>>6, ngrp = bid&63): rows mh*32..+32,
// per-gate cols ngrp*16..+16. Wave w: gate g=w&3, K-half kh=w>>2.
// Single-product f16: 2 m-frags x 16 kcl = 32 MFMA/wave (4 indep chains).
// Gx TIME-MAJOR: step-t slice = contiguous 2MB block.
__global__ __launch_bounds__(512)
void lstm_step(const float* __restrict__ Gx,
               const float* __restrict__ b_hh,
               const char*  __restrict__ Wf,
               char*        __restrict__ hfrag,
               float*       __restrict__ c,
               const float* __restrict__ Wc,
               float*       __restrict__ out,
               int t)
{
    __shared__ short8v Hs[64][64];           // 64 KB: s = mf*32 + kc
    __shared__ float gates_s[2][4][32][16];  // 16 KB
    __shared__ float h_s[32][16];            // 2 KB
    __shared__ float Wc_s[2][16];

    const int tid = threadIdx.x, bid = blockIdx.x;
    const int w = tid >> 6, l = tid & 63;
    const int g = w & 3, kh = w >> 2;
    const int ngrp = bid & 63, mh = bid >> 6;

    if (tid < 32) Wc_s[tid >> 4][tid & 15] =
        Wc[(size_t)(tid >> 4) * 1024 + ngrp * 16 + (tid & 15)];

    const int lhi = l >> 4;
    const int llo = l & 15;

    f32x4 aE0, aO0, aE1, aO1;
#pragma unroll
    for (int r = 0; r < 4; ++r) { aE0[r] = 0.f; aO0[r] = 0.f; aE1[r] = 0.f; aO1[r] = 0.f; }

    if (t > 0) {
        // stage h f16 fragments for m_tiles {2mh, 2mh+1}: 64 slots x 1 KB
        const char* hbase = hfrag + ((t - 1) & 1) * HF2_BUF;
#pragma unroll
        for (int it = 0; it < 8; ++it) {
            const int u  = tid + it * 512;      // 0..4095
            const int s  = u >> 6;              // mf = s>>5, kc = s&31
            const int ln = u & 63;
            Hs[s][ln] = *(const short8v*)(hbase
                        + (size_t)(2 * mh + (s >> 5)) * HF2_MT
                        + (size_t)(s & 31) * 1024 + (size_t)ln * 16);
        }
        __syncthreads();

        const char* wb = Wf + (size_t)((g * 64 + ngrp) * 2 + kh) * 16384 + (size_t)l * 16;
#pragma unroll
        for (int kcl = 0; kcl < 16; kcl += 2) {
            const short8v b0 = *(const short8v*)(wb + kcl * 1024);
            const short8v b1 = *(const short8v*)(wb + (kcl + 1) * 1024);
            const int kc0 = kh * 16 + kcl;
            aE0 = __builtin_amdgcn_mfma_f32_16x16x32_f16(Hs[kc0][l],      b0, aE0, 0, 0, 0);
            aE1 = __builtin_amdgcn_mfma_f32_16x16x32_f16(Hs[32 + kc0][l], b0, aE1, 0, 0, 0);
            aO0 = __builtin_amdgcn_mfma_f32_16x16x32_f16(Hs[kc0 + 1][l],      b1, aO0, 0, 0, 0);
            aO1 = __builtin_amdgcn_mfma_f32_16x16x32_f16(Hs[32 + kc0 + 1][l], b1, aO1, 0, 0, 0);
        }
    }

    // partial gate tiles -> LDS (zeros at t==0); D: col=l&15, row=lhi*4+r
#pragma unroll
    for (int r = 0; r < 4; ++r) {
        gates_s[kh][g][lhi * 4 + r][llo]      = aE0[r] + aO0[r];
        gates_s[kh][g][16 + lhi * 4 + r][llo] = aE1[r] + aO1[r];
    }
    __syncthreads();

    // LSTM cell: 512 threads = 32 rows x 16 cols, one element each
    {
        const int r  = tid >> 4;
        const int cw = tid & 15;
        const int row = mh * 32 + r;
        const int col = ngrp * 16 + cw;
        float gate[4];
#pragma unroll
        for (int gg = 0; gg < 4; ++gg) {
            const size_t gidx = ((size_t)t * 128 + row) * 4096
                              + (size_t)gg * 1024 + col;
            gate[gg] = gates_s[0][gg][r][cw] + gates_s[1][gg][r][cw]
                     + Gx[gidx] + b_hh[gg * 1024 + col];
        }
        float ig = 1.f / (1.f + __expf(-gate[0]));
        float fg = 1.f / (1.f + __expf(-gate[1]));
        float gg = tanhf(gate[2]);
        float og = 1.f / (1.f + __expf(-gate[3]));
        const size_t cidx = (size_t)row * 1024 + col;
        float cp = (t > 0) ? c[cidx] : 0.f;
        float cn = fg * cp + ig * gg;
        float hn = og * tanhf(cn);
        c[cidx] = cn;
        h_s[r][cw] = hn;

        // classifier partial: reduce over 16 cols (cw), then atomicAdd
        float s0 = hn * Wc_s[0][cw];
        float s1 = hn * Wc_s[1][cw];
#pragma unroll
        for (int off = 8; off > 0; off >>= 1) {
            s0 += __shfl_xor(s0, off);
            s1 += __shfl_xor(s1, off);
        }
        if (cw == 0) {
            float* o = out + ((size_t)row * 64 + t) * 2;
            atomicAdd(o,     s0);
            atomicAdd(o + 1, s1);
        }
    }
    __syncthreads();

    // h-fragment write (f16): WG owns kc = ngrp>>1, koct pair (ngrp&1)*2..+1,
    // m_tiles 2mh..2mh+1. 64 threads x 16B chunks.
    // k = (ngrp>>1)*32 + ((ngrp&1)*2+koct_h)*8 + e = ngrp*16 + koct_h*8 + e  ✓
    if (tid < 64) {
        const int idx16  = tid & 15;
        const int koct_h = (tid >> 4) & 1;
        const int mt_l   = (tid >> 5) & 1;
        const int lane   = idx16 | (((ngrp & 1) * 2 + koct_h) << 4);
        short8v v;
#pragma unroll
        for (int e = 0; e < 8; ++e)
            v[e] = f2h(h_s[mt_l * 16 + idx16][koct_h * 8 + e]);
        char* dst = hfrag + (t & 1) * HF2_BUF
                  + (size_t)(2 * mh + mt_l) * HF2_MT
                  + (size_t)(ngrp >> 1) * 1024 + (size_t)lane * 16;
        *(short8v*)dst = v;
    }
}

// ---------------------------------------------------------------------------
extern "C" void kernel_launch(void* const* d_in, const int* in_sizes, int n_in,
                              void* d_out, int out_size, void* d_ws, size_t ws_size,
                              hipStream_t stream) {
    const float* x      = (const float*)d_in[0];
    const float* W_feat = (const float*)d_in[1];
    const float* b_feat = (const float*)d_in[2];
    const float* W_ih   = (const float*)d_in[3];
    const float* b_ih   = (const float*)d_in[4];
    const float* W_hh   = (const float*)d_in[5];
    const float* b_hh   = (const float*)d_in[6];
    const float* W_cls  = (const float*)d_in[7];
    const float* b_cls  = (const float*)d_in[8];
    float* out = (float*)d_out;

    char* ws = (char*)d_ws;
    u16*  F16   = (u16*)ws;                    // [0,16M)  8192x1024 u16 f16
    u16*  Wih16 = (u16*)(ws + 16777216);       // [16,24M) 4096x1024 u16 f16
    u16*  Wf16  = (u16*)(ws + 25165824);       // [24,32M) 1024x4096 u16 f16
    float* Gx   = (float*)(ws + 33554432);     // [32,160M) f32, TIME-MAJOR
    char* Wf    = ws;                          // [0,8M)   whh f16 pack (post-B)
    char* hfrag = ws + 16777216;               // [16,16.5M) post-B (512K dbuf)
    float* c    = (float*)(ws + 17825792);     // [17,17.5M) post-B

    // prep: both weight matrices are 4,194,304 floats = 1,048,576 float4
    cvt_f16<<<dim3(4096), dim3(256), 0, stream>>>(W_feat, Wf16, 1048576);
    cvt_f16<<<dim3(4096), dim3(256), 0, stream>>>(W_ih, Wih16, 1048576);
    out_init<<<dim3(64), dim3(256), 0, stream>>>(out, b_cls);

    // Phase A: F16 = f16(relu(X @ W_feat^T + b_feat))  M=8192 N=1024 K=4096
    gemm_f16<false, true, true, false>
        <<<dim3(64, 8), 256, 0, stream>>>(
            x, nullptr, 4096, Wf16, 4096, b_feat,
            nullptr, F16, 1024, 4096);

    // Phase B: Gx = F16 @ Wih16^T + b_ih   M=8192 N=4096 K=1024, time-major
    gemm_f16<true, false, false, true>
        <<<dim3(64, 32), 256, 0, stream>>>(
            nullptr, F16, 1024, Wih16, 1024, b_ih,
            Gx, nullptr, 4096, 1024);

    // pack W_hh f16 fragments AFTER phase B (aliases dead F16 region)
    pack_whh3<<<dim3(2048), dim3(256), 0, stream>>>(W_hh, Wf);

    // Phase C: 64 fused recurrent steps (per-step launches; see r10 note)
    for (int t = 0; t < 64; ++t) {
        lstm_step<<<dim3(256), dim3(512), 0, stream>>>(
            Gx, b_hh, Wf, hfrag, c, W_cls, out, t);
    }
}